// Round 3
// baseline (1451.886 us; speedup 1.0000x reference)
//
#include <hip/hip_runtime.h>
#include <hip/hip_bf16.h>
#include <math.h>

#define NN 50000
#define NE 800000
#define NREL 4
#define NHEAD 8

typedef __hip_bfloat16 bf16;

__device__ __forceinline__ float b2f(bf16 v) { return __bfloat162float(v); }

// ---------------------------------------------------------------------------
// Diagnostic: fill out with 1000.0 when ws_size is insufficient
// ---------------------------------------------------------------------------
__global__ void fill_kernel(float* __restrict__ out, int n) {
    int t = blockIdx.x * blockDim.x + threadIdx.x;
    if (t < n) out[t] = 1000.0f;
}

// ---------------------------------------------------------------------------
// GEMM1: [NN,128](f32) @ [128, 5*128](f32) -> Xb[4,NN,128] (bf16), S[NN,128] (f32)
// cols 0..511 = W_rel[0..3], cols 512..639 = W_self
// ---------------------------------------------------------------------------
__global__ __launch_bounds__(256) void gemm_node(
    const float* __restrict__ A,      // [NN,128]
    const float* __restrict__ Wrel,   // [4,128,128]
    const float* __restrict__ Wself,  // [128,128]
    bf16* __restrict__ Xb,            // [4,NN,128]
    float* __restrict__ S)            // [NN,128]
{
    const int bm = blockIdx.x;
    const int bn = blockIdx.y;
    const int tid = threadIdx.x;
    const int tx = tid & 15, ty = tid >> 4;

    __shared__ float As[64][33];
    __shared__ float Bs[32][65];

    float acc[4][4] = {};
    const int col0 = bn * 64;
    const int row0 = bm * 64;

    for (int k0 = 0; k0 < 128; k0 += 32) {
        #pragma unroll
        for (int i = 0; i < 8; ++i) {
            int idx = i * 256 + tid;
            int rr = idx >> 5, kk = idx & 31;
            int gr = row0 + rr;
            float v = 0.f;
            if (gr < NN) v = A[gr * 128 + k0 + kk];
            As[rr][kk] = v;
        }
        #pragma unroll
        for (int i = 0; i < 8; ++i) {
            int idx = i * 256 + tid;
            int kk = idx >> 6, cc = idx & 63;
            int gc = col0 + cc;
            int gk = k0 + kk;
            float v;
            if (gc < 512) {
                int r = gc >> 7, c = gc & 127;
                v = Wrel[(r * 128 + gk) * 128 + c];
            } else {
                v = Wself[gk * 128 + (gc - 512)];
            }
            Bs[kk][cc] = v;
        }
        __syncthreads();
        #pragma unroll
        for (int kk = 0; kk < 32; ++kk) {
            float a[4], b[4];
            #pragma unroll
            for (int i = 0; i < 4; ++i) a[i] = As[ty * 4 + i][kk];
            #pragma unroll
            for (int j = 0; j < 4; ++j) b[j] = Bs[kk][tx * 4 + j];
            #pragma unroll
            for (int i = 0; i < 4; ++i)
                #pragma unroll
                for (int j = 0; j < 4; ++j) acc[i][j] += a[i] * b[j];
        }
        __syncthreads();
    }
    #pragma unroll
    for (int i = 0; i < 4; ++i) {
        int gr = row0 + ty * 4 + i;
        if (gr >= NN) continue;
        #pragma unroll
        for (int j = 0; j < 4; ++j) {
            int gc = col0 + tx * 4 + j;
            float v = acc[i][j];
            if (gc < 512) {
                int r = gc >> 7, c = gc & 127;
                Xb[((size_t)(r * NN + gr) << 7) + c] = __float2bfloat16(v);
            } else {
                S[((size_t)gr << 7) + (gc - 512)] = v;
            }
        }
    }
}

// ---------------------------------------------------------------------------
// es/ed: per (r,n,h) 16-wide dot of Xb row-segment with attention vectors
// ---------------------------------------------------------------------------
__global__ void es_ed_kernel(const bf16* __restrict__ Xb,
                             const float* __restrict__ att_src,  // [4,8,16]
                             const float* __restrict__ att_dst,
                             float* __restrict__ es, float* __restrict__ ed)
{
    int t = blockIdx.x * blockDim.x + threadIdx.x;  // (r*NN+n)*8 + h
    if (t >= NREL * NN * NHEAD) return;
    int h = t & 7;
    int rn = t >> 3;
    int r = rn / NN;
    const bf16* xp = Xb + ((size_t)rn << 7) + h * 16;
    const float* as = att_src + (r * 8 + h) * 16;
    const float* ad = att_dst + (r * 8 + h) * 16;
    float s = 0.f, d = 0.f;
    #pragma unroll
    for (int i = 0; i < 16; ++i) {
        float x = b2f(xp[i]);
        s += x * as[i];
        d += x * ad[i];
    }
    es[t] = s;
    ed[t] = d;
}

// ---------------------------------------------------------------------------
// Edge pass for one relation: unnormalized softmax aggregation, fp32 atomics.
// 128 lanes per edge: lane = feature c, h = c>>4. acc is [NN,128] for rel.
// ---------------------------------------------------------------------------
__global__ __launch_bounds__(256) void edge_rel_kernel(
    const int* __restrict__ edge_index, const int* __restrict__ edge_type,
    const bf16* __restrict__ Xb, const float* __restrict__ es,
    const float* __restrict__ ed,
    float* __restrict__ acc, float* __restrict__ den, int rel)
{
    int e = blockIdx.x * 2 + (threadIdx.x >> 7);
    if (e >= NE) return;
    if (edge_type[e] != rel) return;
    int lane = threadIdx.x & 127;
    int src = edge_index[e];
    int dst = edge_index[NE + e];
    int h = lane >> 4;
    size_t rs = (size_t)(rel * NN + src);
    size_t rd = (size_t)(rel * NN + dst);
    float a = es[rs * 8 + h] + ed[rd * 8 + h];
    float l = a > 0.f ? a : 0.2f * a;
    l = fminf(l, 80.f);  // NaN armor; inert on the correct path
    float w = expf(l);
    float x = b2f(Xb[(rs << 7) + lane]);
    unsafeAtomicAdd(&acc[((size_t)dst << 7) + lane], w * x);
    if ((lane & 15) == 0) unsafeAtomicAdd(&den[rd * 8 + h], w);
}

// ---------------------------------------------------------------------------
// normalize + bias + exact GELU for one relation, in place on acc [NN,128]
// ---------------------------------------------------------------------------
__global__ void norm_gelu_kernel(float* __restrict__ acc,
                                 const float* __restrict__ den,
                                 const float* __restrict__ bias_rel, int rel)
{
    int t = blockIdx.x * blockDim.x + threadIdx.x;  // n*128 + c
    if (t >= NN * 128) return;
    int c = t & 127;
    int n = t >> 7;
    int h = c >> 4;
    float dn = den[(size_t)(rel * NN + n) * 8 + h];
    float v = dn > 0.f ? acc[t] / dn : 0.f;
    v += bias_rel[rel * 128 + c];
    float g = 0.5f * v * (1.f + erff(v * 0.70710678118654752f));
    acc[t] = g;
}

// ---------------------------------------------------------------------------
// GEMM2 (per relation): gelu [NN,128](f32) @ W_cross[128,128](f32)
//   -> Hb[rel] [NN,128] (bf16), overwriting Xb[rel] (no longer needed)
// ---------------------------------------------------------------------------
__global__ __launch_bounds__(256) void gemm_cross(
    const float* __restrict__ A,
    const float* __restrict__ W,
    bf16* __restrict__ C)
{
    const int bm = blockIdx.x;
    const int bn = blockIdx.y;
    const int tid = threadIdx.x;
    const int tx = tid & 15, ty = tid >> 4;

    __shared__ float As[64][33];
    __shared__ float Bs[32][65];

    float acc[4][4] = {};
    const int col0 = bn * 64;
    const int row0 = bm * 64;

    for (int k0 = 0; k0 < 128; k0 += 32) {
        #pragma unroll
        for (int i = 0; i < 8; ++i) {
            int idx = i * 256 + tid;
            int rr = idx >> 5, kk = idx & 31;
            int gr = row0 + rr;
            float v = 0.f;
            if (gr < NN) v = A[(size_t)gr * 128 + k0 + kk];
            As[rr][kk] = v;
        }
        #pragma unroll
        for (int i = 0; i < 8; ++i) {
            int idx = i * 256 + tid;
            int kk = idx >> 6, cc = idx & 63;
            Bs[kk][cc] = W[(k0 + kk) * 128 + col0 + cc];
        }
        __syncthreads();
        #pragma unroll
        for (int kk = 0; kk < 32; ++kk) {
            float a[4], b[4];
            #pragma unroll
            for (int i = 0; i < 4; ++i) a[i] = As[ty * 4 + i][kk];
            #pragma unroll
            for (int j = 0; j < 4; ++j) b[j] = Bs[kk][tx * 4 + j];
            #pragma unroll
            for (int i = 0; i < 4; ++i)
                #pragma unroll
                for (int j = 0; j < 4; ++j) acc[i][j] += a[i] * b[j];
        }
        __syncthreads();
    }
    #pragma unroll
    for (int i = 0; i < 4; ++i) {
        int gr = row0 + ty * 4 + i;
        if (gr >= NN) continue;
        #pragma unroll
        for (int j = 0; j < 4; ++j) {
            C[(size_t)gr * 128 + col0 + tx * 4 + j] = __float2bfloat16(acc[i][j]);
        }
    }
}

// ---------------------------------------------------------------------------
// lang conv: per node 5-way softmax over {S, h0..h3}
// ---------------------------------------------------------------------------
__global__ __launch_bounds__(256) void lang_kernel(
    const float* __restrict__ S, const bf16* __restrict__ Hb,
    const float* __restrict__ den,
    const float* __restrict__ att_src_lang, const float* __restrict__ att_dst_lang,
    const float* __restrict__ bias_lang, float* __restrict__ out)
{
    int n = blockIdx.x * 2 + (threadIdx.x >> 7);
    if (n >= NN) return;
    int d = threadIdx.x & 127;
    int h = d >> 4, dd = d & 15;

    float ent[5];
    ent[0] = S[((size_t)n << 7) + d];
    #pragma unroll
    for (int r = 0; r < 4; ++r)
        ent[r + 1] = b2f(Hb[((size_t)(r * NN + n) << 7) + d]);

    float asl = att_src_lang[h * 16 + dd];
    float adl = att_dst_lang[h * 16 + dd];

    float ls[5];
    #pragma unroll
    for (int k = 0; k < 5; ++k) ls[k] = ent[k] * asl;
    float ld = ent[0] * adl;

    // reduce over the 16 lanes of each head (stays within wave64)
    #pragma unroll
    for (int off = 1; off < 16; off <<= 1) {
        #pragma unroll
        for (int k = 0; k < 5; ++k) ls[k] += __shfl_xor(ls[k], off);
        ld += __shfl_xor(ld, off);
    }

    bool valid[5];
    valid[0] = true;
    #pragma unroll
    for (int r = 0; r < 4; ++r)
        valid[r + 1] = den[(size_t)(r * NN + n) * 8] > 0.f;

    float logit[5], m = -1e30f;
    #pragma unroll
    for (int k = 0; k < 5; ++k) {
        float a = ls[k] + ld;
        float l = a > 0.f ? a : 0.2f * a;
        logit[k] = l;
        if (valid[k] && l > m) m = l;
    }
    float sum = 0.f, e[5];
    #pragma unroll
    for (int k = 0; k < 5; ++k) {
        e[k] = valid[k] ? expf(logit[k] - m) : 0.f;
        sum += e[k];
    }
    float o = 0.f;
    #pragma unroll
    for (int k = 0; k < 5; ++k) o += e[k] * ent[k];
    o = o / sum + bias_lang[d];
    out[((size_t)n << 7) + d] = o;
}

// ---------------------------------------------------------------------------
extern "C" void kernel_launch(void* const* d_in, const int* in_sizes, int n_in,
                              void* d_out, int out_size, void* d_ws, size_t ws_size,
                              hipStream_t stream) {
    const float* node_inp     = (const float*)d_in[0];
    const int*   edge_index   = (const int*)d_in[1];
    const int*   edge_type    = (const int*)d_in[2];
    const float* W_rel        = (const float*)d_in[3];
    const float* att_src_rel  = (const float*)d_in[4];
    const float* att_dst_rel  = (const float*)d_in[5];
    const float* bias_rel     = (const float*)d_in[6];
    const float* W_self       = (const float*)d_in[7];
    const float* W_cross      = (const float*)d_in[8];
    const float* att_src_lang = (const float*)d_in[9];
    const float* att_dst_lang = (const float*)d_in[10];
    const float* bias_lang    = (const float*)d_in[11];
    (void)in_sizes; (void)n_in;

    // workspace layout (bytes) — total 121,600,000 (known to fit from R2 probe)
    const size_t SZ_XB  = (size_t)NREL * NN * 128 * 2;  // 51,200,000 (bf16)
    const size_t SZ_S   = (size_t)NN * 128 * 4;         // 25,600,000
    const size_t SZ_ACC = (size_t)NN * 128 * 4;         // 25,600,000
    const size_t SZ_DEN = (size_t)NREL * NN * 8 * 4;    //  6,400,000
    const size_t SZ_ES  = SZ_DEN;
    const size_t TOTAL  = SZ_XB + SZ_S + SZ_ACC + SZ_DEN + 2 * SZ_ES;

    if (ws_size < TOTAL) {
        // diagnostic signature: absmax ~1000 => workspace too small
        fill_kernel<<<(out_size + 255) / 256, 256, 0, stream>>>((float*)d_out, out_size);
        return;
    }

    char* ws = (char*)d_ws;
    bf16*  Xb  = (bf16*)(ws);
    float* S   = (float*)(ws + SZ_XB);
    float* acc = (float*)(ws + SZ_XB + SZ_S);
    float* den = (float*)(ws + SZ_XB + SZ_S + SZ_ACC);
    float* es  = (float*)(ws + SZ_XB + SZ_S + SZ_ACC + SZ_DEN);
    float* ed  = (float*)(ws + SZ_XB + SZ_S + SZ_ACC + SZ_DEN + SZ_ES);

    hipMemsetAsync(den, 0, SZ_DEN, stream);

    dim3 g1((NN + 63) / 64, 10);
    gemm_node<<<g1, 256, 0, stream>>>(node_inp, W_rel, W_self, Xb, S);

    int ne_t = NREL * NN * NHEAD;
    es_ed_kernel<<<(ne_t + 255) / 256, 256, 0, stream>>>(Xb, att_src_rel, att_dst_rel, es, ed);

    dim3 g2((NN + 63) / 64, 2);
    for (int r = 0; r < NREL; ++r) {
        hipMemsetAsync(acc, 0, SZ_ACC, stream);
        edge_rel_kernel<<<NE / 2, 256, 0, stream>>>(edge_index, edge_type, Xb, es, ed,
                                                    acc, den, r);
        norm_gelu_kernel<<<(NN * 128 + 255) / 256, 256, 0, stream>>>(acc, den, bias_rel, r);
        gemm_cross<<<g2, 256, 0, stream>>>(acc, W_cross, Xb + (size_t)r * NN * 128);
    }

    lang_kernel<<<NN / 2, 256, 0, stream>>>(S, Xb, den, att_src_lang, att_dst_lang,
                                            bias_lang, (float*)d_out);
}

// Round 4
// 1061.819 us; speedup vs baseline: 1.3674x; 1.3674x over previous
//
#include <hip/hip_runtime.h>
#include <hip/hip_bf16.h>
#include <math.h>

#define NN 50000
#define NE 800000
#define NREL 4
#define NHEAD 8

typedef __hip_bfloat16 bf16;
typedef short short8 __attribute__((ext_vector_type(8)));
typedef float floatx4 __attribute__((ext_vector_type(4)));

__device__ __forceinline__ float b2f(bf16 v) { return __bfloat162float(v); }

// ---------------------------------------------------------------------------
// Diagnostic: fill out with 1000.0 when ws_size is insufficient
// ---------------------------------------------------------------------------
__global__ void fill_kernel(float* __restrict__ out, int n) {
    int t = blockIdx.x * blockDim.x + threadIdx.x;
    if (t < n) out[t] = 1000.0f;
}

// ---------------------------------------------------------------------------
// Convert node_inp fp32 -> bf16
// ---------------------------------------------------------------------------
__global__ void conv_node_kernel(const float* __restrict__ A, bf16* __restrict__ Ab) {
    int t = blockIdx.x * blockDim.x + threadIdx.x;
    if (t < NN * 128) Ab[t] = __float2bfloat16(A[t]);
}

// ---------------------------------------------------------------------------
// Pack weights, transposed to [col][k] bf16 for MFMA B-operand staging.
// Wt[640][128]: cols 0..511 = W_rel[r][:, c], cols 512..639 = W_self[:, c]
// Wct[128][128]: W_cross transposed
// ---------------------------------------------------------------------------
__global__ void conv_w_kernel(const float* __restrict__ W_rel,
                              const float* __restrict__ W_self,
                              const float* __restrict__ W_cross,
                              bf16* __restrict__ Wt, bf16* __restrict__ Wct) {
    int t = blockIdx.x * blockDim.x + threadIdx.x;
    if (t < 640 * 128) {
        int col = t >> 7, k = t & 127;
        float v;
        if (col < 512) {
            int r = col >> 7, c = col & 127;
            v = W_rel[(r * 128 + k) * 128 + c];
        } else {
            v = W_self[k * 128 + (col - 512)];
        }
        Wt[t] = __float2bfloat16(v);
    } else if (t < 640 * 128 + 128 * 128) {
        int u = t - 640 * 128;
        int n = u >> 7, k = u & 127;
        Wct[u] = __float2bfloat16(W_cross[k * 128 + n]);
    }
}

// ---------------------------------------------------------------------------
// MFMA GEMM: A[M,128] bf16 (k-contig) @ Bt[Ncols,128] bf16 (k-contig, i.e. B^T)
// MODE 0: Ncols=640 grid.y=5 -> cols<512 to Xb[4,NN,128] bf16, cols>=512 to S f32
// MODE 1: Ncols=128 grid.y=1 -> outb[M,128] bf16
// Block: 256 thr = 4 waves; 128x128 C-tile; wave = 64x64 quadrant (4x4 of 16x16)
// ---------------------------------------------------------------------------
template<int MODE>
__global__ __launch_bounds__(256) void gemm_mfma(
    const bf16* __restrict__ A,
    const bf16* __restrict__ Bt,
    bf16* __restrict__ outb,
    float* __restrict__ outf,
    int M)
{
    __shared__ __align__(16) short As[128][40];
    __shared__ __align__(16) short Bs[128][40];
    const int tid  = threadIdx.x;
    const int wave = tid >> 6, lane = tid & 63;
    const int quad = lane >> 4, l16 = lane & 15;
    const int wq = wave >> 1, wc = wave & 1;
    const int row0 = blockIdx.x * 128;
    const int col0 = blockIdx.y * 128;

    floatx4 acc[4][4];
    #pragma unroll
    for (int i = 0; i < 4; ++i)
        #pragma unroll
        for (int j = 0; j < 4; ++j) acc[i][j] = (floatx4){0.f, 0.f, 0.f, 0.f};

    for (int k0 = 0; k0 < 128; k0 += 32) {
        #pragma unroll
        for (int i = 0; i < 2; ++i) {
            int c = tid * 2 + i;                 // 0..511 chunks of 8 bf16
            int r = c >> 2, off = (c & 3) * 8;
            int gr = row0 + r;
            short8 v = {0, 0, 0, 0, 0, 0, 0, 0};
            if (gr < M) v = *(const short8*)(A + (((size_t)gr) << 7) + k0 + off);
            *(short8*)&As[r][off] = v;
            short8 w = *(const short8*)(Bt + (((size_t)(col0 + r)) << 7) + k0 + off);
            *(short8*)&Bs[r][off] = w;
        }
        __syncthreads();

        short8 av[4], bv[4];
        #pragma unroll
        for (int mt = 0; mt < 4; ++mt)
            av[mt] = *(const short8*)&As[wq * 64 + mt * 16 + l16][quad * 8];
        #pragma unroll
        for (int nt = 0; nt < 4; ++nt)
            bv[nt] = *(const short8*)&Bs[wc * 64 + nt * 16 + l16][quad * 8];
        #pragma unroll
        for (int mt = 0; mt < 4; ++mt)
            #pragma unroll
            for (int nt = 0; nt < 4; ++nt)
                acc[mt][nt] = __builtin_amdgcn_mfma_f32_16x16x32_bf16(
                    av[mt], bv[nt], acc[mt][nt], 0, 0, 0);
        __syncthreads();
    }

    #pragma unroll
    for (int mt = 0; mt < 4; ++mt) {
        #pragma unroll
        for (int reg = 0; reg < 4; ++reg) {
            int gr = row0 + wq * 64 + mt * 16 + quad * 4 + reg;
            if (gr >= M) continue;
            #pragma unroll
            for (int nt = 0; nt < 4; ++nt) {
                int gc = col0 + wc * 64 + nt * 16 + l16;
                float v = acc[mt][nt][reg];
                if (MODE == 0) {
                    if (gc < 512) {
                        int r = gc >> 7, c = gc & 127;
                        outb[((size_t)(r * NN + gr) << 7) + c] = __float2bfloat16(v);
                    } else {
                        outf[(((size_t)gr) << 7) + (gc - 512)] = v;
                    }
                } else {
                    outb[(((size_t)gr) << 7) + gc] = __float2bfloat16(v);
                }
            }
        }
    }
}

// ---------------------------------------------------------------------------
// es/ed: per (r,n,h) 16-wide dot of Xb row-segment with attention vectors
// ---------------------------------------------------------------------------
__global__ void es_ed_kernel(const bf16* __restrict__ Xb,
                             const float* __restrict__ att_src,  // [4,8,16]
                             const float* __restrict__ att_dst,
                             float* __restrict__ es, float* __restrict__ ed)
{
    int t = blockIdx.x * blockDim.x + threadIdx.x;  // (r*NN+n)*8 + h
    if (t >= NREL * NN * NHEAD) return;
    int h = t & 7;
    int rn = t >> 3;
    int r = rn / NN;
    const bf16* xp = Xb + ((size_t)rn << 7) + h * 16;
    const float* as = att_src + (r * 8 + h) * 16;
    const float* ad = att_dst + (r * 8 + h) * 16;
    float s = 0.f, d = 0.f;
    #pragma unroll
    for (int i = 0; i < 16; ++i) {
        float x = b2f(xp[i]);
        s += x * as[i];
        d += x * ad[i];
    }
    es[t] = s;
    ed[t] = d;
}

// ---------------------------------------------------------------------------
// Edge pass for one relation: unnormalized softmax aggregation, fp32 atomics.
// 128 lanes per edge: lane = feature c, h = c>>4. acc is [NN,128] for rel.
// ---------------------------------------------------------------------------
__global__ __launch_bounds__(256) void edge_rel_kernel(
    const int* __restrict__ edge_index, const int* __restrict__ edge_type,
    const bf16* __restrict__ Xb, const float* __restrict__ es,
    const float* __restrict__ ed,
    float* __restrict__ acc, float* __restrict__ den, int rel)
{
    int e = blockIdx.x * 2 + (threadIdx.x >> 7);
    if (e >= NE) return;
    if (edge_type[e] != rel) return;
    int lane = threadIdx.x & 127;
    int src = edge_index[e];
    int dst = edge_index[NE + e];
    int h = lane >> 4;
    size_t rs = (size_t)(rel * NN + src);
    size_t rd = (size_t)(rel * NN + dst);
    float a = es[rs * 8 + h] + ed[rd * 8 + h];
    float l = a > 0.f ? a : 0.2f * a;
    l = fminf(l, 80.f);  // NaN armor; inert on the correct path
    float w = expf(l);
    float x = b2f(Xb[(rs << 7) + lane]);
    unsafeAtomicAdd(&acc[((size_t)dst << 7) + lane], w * x);
    if ((lane & 15) == 0) unsafeAtomicAdd(&den[rd * 8 + h], w);
}

// ---------------------------------------------------------------------------
// normalize + bias + exact GELU for one relation: acc f32 -> Gb bf16
// ---------------------------------------------------------------------------
__global__ void norm_gelu_kernel(const float* __restrict__ acc,
                                 const float* __restrict__ den,
                                 const float* __restrict__ bias_rel,
                                 bf16* __restrict__ Gb, int rel)
{
    int t = blockIdx.x * blockDim.x + threadIdx.x;  // n*128 + c
    if (t >= NN * 128) return;
    int c = t & 127;
    int n = t >> 7;
    int h = c >> 4;
    float dn = den[(size_t)(rel * NN + n) * 8 + h];
    float v = dn > 0.f ? acc[t] / dn : 0.f;
    v += bias_rel[rel * 128 + c];
    float g = 0.5f * v * (1.f + erff(v * 0.70710678118654752f));
    Gb[t] = __float2bfloat16(g);
}

// ---------------------------------------------------------------------------
// lang conv: per node 5-way softmax over {S, h0..h3}; S lives in `out`
// (each thread reads its own element before overwriting it)
// ---------------------------------------------------------------------------
__global__ __launch_bounds__(256) void lang_kernel(
    const float* __restrict__ S, const bf16* __restrict__ Hb,
    const float* __restrict__ den,
    const float* __restrict__ att_src_lang, const float* __restrict__ att_dst_lang,
    const float* __restrict__ bias_lang, float* __restrict__ out)
{
    int n = blockIdx.x * 2 + (threadIdx.x >> 7);
    if (n >= NN) return;
    int d = threadIdx.x & 127;
    int h = d >> 4, dd = d & 15;

    float ent[5];
    ent[0] = S[((size_t)n << 7) + d];
    #pragma unroll
    for (int r = 0; r < 4; ++r)
        ent[r + 1] = b2f(Hb[((size_t)(r * NN + n) << 7) + d]);

    float asl = att_src_lang[h * 16 + dd];
    float adl = att_dst_lang[h * 16 + dd];

    float ls[5];
    #pragma unroll
    for (int k = 0; k < 5; ++k) ls[k] = ent[k] * asl;
    float ld = ent[0] * adl;

    #pragma unroll
    for (int off = 1; off < 16; off <<= 1) {
        #pragma unroll
        for (int k = 0; k < 5; ++k) ls[k] += __shfl_xor(ls[k], off);
        ld += __shfl_xor(ld, off);
    }

    bool valid[5];
    valid[0] = true;
    #pragma unroll
    for (int r = 0; r < 4; ++r)
        valid[r + 1] = den[(size_t)(r * NN + n) * 8] > 0.f;

    float logit[5], m = -1e30f;
    #pragma unroll
    for (int k = 0; k < 5; ++k) {
        float a = ls[k] + ld;
        float l = a > 0.f ? a : 0.2f * a;
        logit[k] = l;
        if (valid[k] && l > m) m = l;
    }
    float sum = 0.f, e[5];
    #pragma unroll
    for (int k = 0; k < 5; ++k) {
        e[k] = valid[k] ? expf(logit[k] - m) : 0.f;
        sum += e[k];
    }
    float o = 0.f;
    #pragma unroll
    for (int k = 0; k < 5; ++k) o += e[k] * ent[k];
    o = o / sum + bias_lang[d];
    out[((size_t)n << 7) + d] = o;
}

// ---------------------------------------------------------------------------
extern "C" void kernel_launch(void* const* d_in, const int* in_sizes, int n_in,
                              void* d_out, int out_size, void* d_ws, size_t ws_size,
                              hipStream_t stream) {
    const float* node_inp     = (const float*)d_in[0];
    const int*   edge_index   = (const int*)d_in[1];
    const int*   edge_type    = (const int*)d_in[2];
    const float* W_rel        = (const float*)d_in[3];
    const float* att_src_rel  = (const float*)d_in[4];
    const float* att_dst_rel  = (const float*)d_in[5];
    const float* bias_rel     = (const float*)d_in[6];
    const float* W_self       = (const float*)d_in[7];
    const float* W_cross      = (const float*)d_in[8];
    const float* att_src_lang = (const float*)d_in[9];
    const float* att_dst_lang = (const float*)d_in[10];
    const float* bias_lang    = (const float*)d_in[11];
    (void)in_sizes; (void)n_in;

    // workspace layout (bytes) — total 108,996,608 (< 121.6 MB known-fit)
    const size_t SZ_XB  = (size_t)NREL * NN * 128 * 2;  // 51,200,000 (bf16)
    const size_t SZ_ACC = (size_t)NN * 128 * 4;         // 25,600,000
    const size_t SZ_DEN = (size_t)NREL * NN * 8 * 4;    //  6,400,000
    const size_t SZ_ES  = SZ_DEN;
    const size_t SZ_AB  = (size_t)NN * 128 * 2;         // 12,800,000 (Ab/Gb shared)
    const size_t SZ_WT  = 640 * 128 * 2;                //    163,840
    const size_t SZ_WCT = 128 * 128 * 2;                //     32,768
    const size_t TOTAL  = SZ_XB + SZ_ACC + SZ_DEN + 2 * SZ_ES + SZ_AB + SZ_WT + SZ_WCT;

    if (ws_size < TOTAL) {
        fill_kernel<<<(out_size + 255) / 256, 256, 0, stream>>>((float*)d_out, out_size);
        return;
    }

    char* ws = (char*)d_ws;
    bf16*  Xb  = (bf16*)(ws);
    float* acc = (float*)(ws + SZ_XB);
    float* den = (float*)(ws + SZ_XB + SZ_ACC);
    float* es  = (float*)(ws + SZ_XB + SZ_ACC + SZ_DEN);
    float* ed  = (float*)(ws + SZ_XB + SZ_ACC + SZ_DEN + SZ_ES);
    bf16*  Ab  = (bf16*)(ws + SZ_XB + SZ_ACC + SZ_DEN + 2 * SZ_ES);  // also Gb
    bf16*  Wt  = (bf16*)(ws + SZ_XB + SZ_ACC + SZ_DEN + 2 * SZ_ES + SZ_AB);
    bf16*  Wct = (bf16*)(ws + SZ_XB + SZ_ACC + SZ_DEN + 2 * SZ_ES + SZ_AB + SZ_WT);
    float* S   = (float*)d_out;  // S scratch lives in d_out; lang_kernel overwrites

    hipMemsetAsync(den, 0, SZ_DEN, stream);

    conv_node_kernel<<<(NN * 128 + 255) / 256, 256, 0, stream>>>(node_inp, Ab);
    conv_w_kernel<<<(768 * 128 + 255) / 256, 256, 0, stream>>>(W_rel, W_self, W_cross, Wt, Wct);

    dim3 g1((NN + 127) / 128, 5);
    gemm_mfma<0><<<g1, 256, 0, stream>>>(Ab, Wt, Xb, S, NN);

    int ne_t = NREL * NN * NHEAD;
    es_ed_kernel<<<(ne_t + 255) / 256, 256, 0, stream>>>(Xb, att_src_rel, att_dst_rel, es, ed);

    dim3 g2((NN + 127) / 128, 1);
    bf16* Gb = Ab;  // Ab dead after gemm_mfma<0>
    for (int r = 0; r < NREL; ++r) {
        hipMemsetAsync(acc, 0, SZ_ACC, stream);
        edge_rel_kernel<<<NE / 2, 256, 0, stream>>>(edge_index, edge_type, Xb, es, ed,
                                                    acc, den, r);
        norm_gelu_kernel<<<(NN * 128 + 255) / 256, 256, 0, stream>>>(acc, den, bias_rel, Gb, r);
        gemm_mfma<1><<<g2, 256, 0, stream>>>(Gb, Wct, Xb + (size_t)r * NN * 128, nullptr, NN);
    }

    lang_kernel<<<NN / 2, 256, 0, stream>>>(S, Xb, den, att_src_lang, att_dst_lang,
                                            bias_lang, (float*)d_out);
}

// Round 5
// 452.629 us; speedup vs baseline: 3.2077x; 2.3459x over previous
//
#include <hip/hip_runtime.h>
#include <hip/hip_bf16.h>
#include <math.h>

#define NN 50000
#define NE 800000
#define NREL 4
#define NHEAD 8
#define NSEG (NREL * NN)            // 200000 (rel,dst) segments
#define NPART ((NSEG + 255) / 256)  // 782 scan partials

typedef __hip_bfloat16 bf16;
typedef short short8 __attribute__((ext_vector_type(8)));
typedef float floatx4 __attribute__((ext_vector_type(4)));

__device__ __forceinline__ float b2f(bf16 v) { return __bfloat162float(v); }

// ---------------------------------------------------------------------------
// Diagnostic: fill out with 1000.0 when ws_size is insufficient
// ---------------------------------------------------------------------------
__global__ void fill_kernel(float* __restrict__ out, int n) {
    int t = blockIdx.x * blockDim.x + threadIdx.x;
    if (t < n) out[t] = 1000.0f;
}

// ---------------------------------------------------------------------------
// Convert node_inp fp32 -> bf16
// ---------------------------------------------------------------------------
__global__ void conv_node_kernel(const float* __restrict__ A, bf16* __restrict__ Ab) {
    int t = blockIdx.x * blockDim.x + threadIdx.x;
    if (t < NN * 128) Ab[t] = __float2bfloat16(A[t]);
}

// ---------------------------------------------------------------------------
// Pack weights, transposed to [col][k] bf16 for MFMA B-operand staging.
// ---------------------------------------------------------------------------
__global__ void conv_w_kernel(const float* __restrict__ W_rel,
                              const float* __restrict__ W_self,
                              const float* __restrict__ W_cross,
                              bf16* __restrict__ Wt, bf16* __restrict__ Wct) {
    int t = blockIdx.x * blockDim.x + threadIdx.x;
    if (t < 640 * 128) {
        int col = t >> 7, k = t & 127;
        float v;
        if (col < 512) {
            int r = col >> 7, c = col & 127;
            v = W_rel[(r * 128 + k) * 128 + c];
        } else {
            v = W_self[k * 128 + (col - 512)];
        }
        Wt[t] = __float2bfloat16(v);
    } else if (t < 640 * 128 + 128 * 128) {
        int u = t - 640 * 128;
        int n = u >> 7, k = u & 127;
        Wct[u] = __float2bfloat16(W_cross[k * 128 + n]);
    }
}

// ---------------------------------------------------------------------------
// MFMA GEMM (verified R4): A[M,128] bf16 @ Bt[Ncols,128] bf16 (B^T layout)
// MODE 0: grid.y=5 -> cols<512 to Xb[4,NN,128] bf16, cols>=512 to S f32
// MODE 1: grid.y=1 -> outb[M,128] bf16
// ---------------------------------------------------------------------------
template<int MODE>
__global__ __launch_bounds__(256) void gemm_mfma(
    const bf16* __restrict__ A,
    const bf16* __restrict__ Bt,
    bf16* __restrict__ outb,
    float* __restrict__ outf,
    int M)
{
    __shared__ __align__(16) short As[128][40];
    __shared__ __align__(16) short Bs[128][40];
    const int tid  = threadIdx.x;
    const int wave = tid >> 6, lane = tid & 63;
    const int quad = lane >> 4, l16 = lane & 15;
    const int wq = wave >> 1, wc = wave & 1;
    const int row0 = blockIdx.x * 128;
    const int col0 = blockIdx.y * 128;

    floatx4 acc[4][4];
    #pragma unroll
    for (int i = 0; i < 4; ++i)
        #pragma unroll
        for (int j = 0; j < 4; ++j) acc[i][j] = (floatx4){0.f, 0.f, 0.f, 0.f};

    for (int k0 = 0; k0 < 128; k0 += 32) {
        #pragma unroll
        for (int i = 0; i < 2; ++i) {
            int c = tid * 2 + i;
            int r = c >> 2, off = (c & 3) * 8;
            int gr = row0 + r;
            short8 v = {0, 0, 0, 0, 0, 0, 0, 0};
            if (gr < M) v = *(const short8*)(A + (((size_t)gr) << 7) + k0 + off);
            *(short8*)&As[r][off] = v;
            short8 w = *(const short8*)(Bt + (((size_t)(col0 + r)) << 7) + k0 + off);
            *(short8*)&Bs[r][off] = w;
        }
        __syncthreads();

        short8 av[4], bv[4];
        #pragma unroll
        for (int mt = 0; mt < 4; ++mt)
            av[mt] = *(const short8*)&As[wq * 64 + mt * 16 + l16][quad * 8];
        #pragma unroll
        for (int nt = 0; nt < 4; ++nt)
            bv[nt] = *(const short8*)&Bs[wc * 64 + nt * 16 + l16][quad * 8];
        #pragma unroll
        for (int mt = 0; mt < 4; ++mt)
            #pragma unroll
            for (int nt = 0; nt < 4; ++nt)
                acc[mt][nt] = __builtin_amdgcn_mfma_f32_16x16x32_bf16(
                    av[mt], bv[nt], acc[mt][nt], 0, 0, 0);
        __syncthreads();
    }

    #pragma unroll
    for (int mt = 0; mt < 4; ++mt) {
        #pragma unroll
        for (int reg = 0; reg < 4; ++reg) {
            int gr = row0 + wq * 64 + mt * 16 + quad * 4 + reg;
            if (gr >= M) continue;
            #pragma unroll
            for (int nt = 0; nt < 4; ++nt) {
                int gc = col0 + wc * 64 + nt * 16 + l16;
                float v = acc[mt][nt][reg];
                if (MODE == 0) {
                    if (gc < 512) {
                        int r = gc >> 7, c = gc & 127;
                        outb[((size_t)(r * NN + gr) << 7) + c] = __float2bfloat16(v);
                    } else {
                        outf[(((size_t)gr) << 7) + (gc - 512)] = v;
                    }
                } else {
                    outb[(((size_t)gr) << 7) + gc] = __float2bfloat16(v);
                }
            }
        }
    }
}

// ---------------------------------------------------------------------------
// es/ed: per (r,n,h) 16-wide dot of Xb row-segment with attention vectors
// ---------------------------------------------------------------------------
__global__ void es_ed_kernel(const bf16* __restrict__ Xb,
                             const float* __restrict__ att_src,
                             const float* __restrict__ att_dst,
                             float* __restrict__ es, float* __restrict__ ed)
{
    int t = blockIdx.x * blockDim.x + threadIdx.x;
    if (t >= NREL * NN * NHEAD) return;
    int h = t & 7;
    int rn = t >> 3;
    int r = rn / NN;
    const bf16* xp = Xb + ((size_t)rn << 7) + h * 16;
    const float* as = att_src + (r * 8 + h) * 16;
    const float* ad = att_dst + (r * 8 + h) * 16;
    float s = 0.f, d = 0.f;
    #pragma unroll
    for (int i = 0; i < 16; ++i) {
        float x = b2f(xp[i]);
        s += x * as[i];
        d += x * ad[i];
    }
    es[t] = s;
    ed[t] = d;
}

// ---------------------------------------------------------------------------
// Counting sort of edges by seg = rel*NN + dst  (histogram / scan / scatter)
// ---------------------------------------------------------------------------
__global__ void hist_kernel(const int* __restrict__ ei, const int* __restrict__ et,
                            int* __restrict__ counts) {
    int e = blockIdx.x * 256 + threadIdx.x;
    if (e >= NE) return;
    int seg = et[e] * NN + ei[NE + e];
    atomicAdd(&counts[seg], 1);
}

__global__ __launch_bounds__(256) void scan1_kernel(const int* __restrict__ counts,
                                                    int* __restrict__ offsets,
                                                    int* __restrict__ partials) {
    __shared__ int sm[256];
    int b = blockIdx.x, t = threadIdx.x, i = b * 256 + t;
    int v = (i < NSEG) ? counts[i] : 0;
    sm[t] = v;
    __syncthreads();
    #pragma unroll
    for (int off = 1; off < 256; off <<= 1) {
        int x = sm[t];
        int y = (t >= off) ? sm[t - off] : 0;
        __syncthreads();
        sm[t] = x + y;
        __syncthreads();
    }
    if (i < NSEG) offsets[i] = sm[t] - v;   // chunk-local exclusive
    if (t == 255) partials[b] = sm[255];
}

__global__ __launch_bounds__(1024) void scan2_kernel(int* __restrict__ partials,
                                                     int* __restrict__ offsets) {
    __shared__ int sm[1024];
    int t = threadIdx.x;
    int v = (t < NPART) ? partials[t] : 0;
    sm[t] = v;
    __syncthreads();
    #pragma unroll
    for (int off = 1; off < 1024; off <<= 1) {
        int x = sm[t];
        int y = (t >= off) ? sm[t - off] : 0;
        __syncthreads();
        sm[t] = x + y;
        __syncthreads();
    }
    if (t < NPART) partials[t] = sm[t] - v;  // exclusive partial prefix
    if (t == 0) offsets[NSEG] = NE;
}

__global__ __launch_bounds__(256) void scan3_kernel(int* __restrict__ offsets,
                                                    const int* __restrict__ partials,
                                                    int* __restrict__ cursor) {
    int b = blockIdx.x, i = b * 256 + threadIdx.x;
    if (i >= NSEG) return;
    int v = offsets[i] + partials[b];
    offsets[i] = v;
    cursor[i] = v;
}

__global__ void scatter_kernel(const int* __restrict__ ei, const int* __restrict__ et,
                               int* __restrict__ cursor, int* __restrict__ esrc) {
    int e = blockIdx.x * 256 + threadIdx.x;
    if (e >= NE) return;
    int seg = et[e] * NN + ei[NE + e];
    int pos = atomicAdd(&cursor[seg], 1);
    esrc[pos] = ei[e];
}

// ---------------------------------------------------------------------------
// Aggregation for one relation: 64 lanes per dst node walk its CSR slice,
// accumulate w*Xb[src] in registers, fuse normalize+bias+GELU -> Gb bf16.
// lane l covers features {2l, 2l+1}; head h = l>>3.
// ---------------------------------------------------------------------------
__global__ __launch_bounds__(256) void agg_rel_kernel(
    const int* __restrict__ esrc, const int* __restrict__ offsets,
    const bf16* __restrict__ Xb, const float* __restrict__ es,
    const float* __restrict__ ed, const float* __restrict__ bias_rel,
    bf16* __restrict__ Gb, int rel)
{
    int n = blockIdx.x * 4 + (threadIdx.x >> 6);
    if (n >= NN) return;
    int l = threadIdx.x & 63;
    int h = l >> 3;
    int f = l * 2;
    int seg = rel * NN + n;
    int beg = offsets[seg], end = offsets[seg + 1];
    float edv = ed[(size_t)seg * 8 + h];
    float a0 = 0.f, a1 = 0.f, den = 0.f;
    const bf16* Xr = Xb + (((size_t)rel * NN) << 7);
    for (int e = beg; e < end; ++e) {
        int src = esrc[e];
        float aa = es[(size_t)(rel * NN + src) * 8 + h] + edv;
        float lg = aa > 0.f ? aa : 0.2f * aa;
        float w = expf(fminf(lg, 80.f));
        ushort2 u = *(const ushort2*)((const unsigned short*)Xr + (((size_t)src) << 7) + f);
        bf16 bx0 = *(bf16*)&u.x, bx1 = *(bf16*)&u.y;
        a0 += w * b2f(bx0);
        a1 += w * b2f(bx1);
        den += w;
    }
    float inv = den > 0.f ? 1.f / den : 0.f;
    float v0 = a0 * inv + bias_rel[rel * 128 + f];
    float v1 = a1 * inv + bias_rel[rel * 128 + f + 1];
    v0 = 0.5f * v0 * (1.f + erff(v0 * 0.70710678118654752f));
    v1 = 0.5f * v1 * (1.f + erff(v1 * 0.70710678118654752f));
    bf16 g0 = __float2bfloat16(v0), g1 = __float2bfloat16(v1);
    ushort2 o;
    o.x = *(unsigned short*)&g0;
    o.y = *(unsigned short*)&g1;
    *(ushort2*)((unsigned short*)Gb + (((size_t)n) << 7) + f) = o;
}

// ---------------------------------------------------------------------------
// lang conv: per node 5-way softmax over {S, h0..h3}; S lives in `out`.
// Validity of relation r at node n: CSR segment non-empty.
// ---------------------------------------------------------------------------
__global__ __launch_bounds__(256) void lang_kernel(
    const float* __restrict__ S, const bf16* __restrict__ Hb,
    const int* __restrict__ offsets,
    const float* __restrict__ att_src_lang, const float* __restrict__ att_dst_lang,
    const float* __restrict__ bias_lang, float* __restrict__ out)
{
    int n = blockIdx.x * 2 + (threadIdx.x >> 7);
    if (n >= NN) return;
    int d = threadIdx.x & 127;
    int h = d >> 4, dd = d & 15;

    float ent[5];
    ent[0] = S[((size_t)n << 7) + d];
    #pragma unroll
    for (int r = 0; r < 4; ++r)
        ent[r + 1] = b2f(Hb[((size_t)(r * NN + n) << 7) + d]);

    float asl = att_src_lang[h * 16 + dd];
    float adl = att_dst_lang[h * 16 + dd];

    float ls[5];
    #pragma unroll
    for (int k = 0; k < 5; ++k) ls[k] = ent[k] * asl;
    float ld = ent[0] * adl;

    #pragma unroll
    for (int off = 1; off < 16; off <<= 1) {
        #pragma unroll
        for (int k = 0; k < 5; ++k) ls[k] += __shfl_xor(ls[k], off);
        ld += __shfl_xor(ld, off);
    }

    bool valid[5];
    valid[0] = true;
    #pragma unroll
    for (int r = 0; r < 4; ++r) {
        int seg = r * NN + n;
        valid[r + 1] = offsets[seg + 1] > offsets[seg];
    }

    float logit[5], m = -1e30f;
    #pragma unroll
    for (int k = 0; k < 5; ++k) {
        float a = ls[k] + ld;
        float l = a > 0.f ? a : 0.2f * a;
        logit[k] = l;
        if (valid[k] && l > m) m = l;
    }
    float sum = 0.f, e[5];
    #pragma unroll
    for (int k = 0; k < 5; ++k) {
        e[k] = valid[k] ? expf(logit[k] - m) : 0.f;
        sum += e[k];
    }
    float o = 0.f;
    #pragma unroll
    for (int k = 0; k < 5; ++k) o += e[k] * ent[k];
    o = o / sum + bias_lang[d];
    out[((size_t)n << 7) + d] = o;
}

// ---------------------------------------------------------------------------
extern "C" void kernel_launch(void* const* d_in, const int* in_sizes, int n_in,
                              void* d_out, int out_size, void* d_ws, size_t ws_size,
                              hipStream_t stream) {
    const float* node_inp     = (const float*)d_in[0];
    const int*   edge_index   = (const int*)d_in[1];
    const int*   edge_type    = (const int*)d_in[2];
    const float* W_rel        = (const float*)d_in[3];
    const float* att_src_rel  = (const float*)d_in[4];
    const float* att_dst_rel  = (const float*)d_in[5];
    const float* bias_rel     = (const float*)d_in[6];
    const float* W_self       = (const float*)d_in[7];
    const float* W_cross      = (const float*)d_in[8];
    const float* att_src_lang = (const float*)d_in[9];
    const float* att_dst_lang = (const float*)d_in[10];
    const float* bias_lang    = (const float*)d_in[11];
    (void)in_sizes; (void)n_in;

    // workspace layout (bytes) — total ~82.6 MB
    const size_t SZ_XB   = (size_t)NREL * NN * 128 * 2;   // 51,200,000 (bf16)
    const size_t SZ_ES   = (size_t)NREL * NN * 8 * 4;     //  6,400,000
    const size_t SZ_AB   = (size_t)NN * 128 * 2;          // 12,800,000 (Ab/Gb shared)
    const size_t SZ_WT   = 640 * 128 * 2;                 //    163,840
    const size_t SZ_WCT  = 128 * 128 * 2;                 //     32,768
    const size_t SZ_ESRC = (size_t)NE * 4;                //  3,200,000
    const size_t SZ_OFF  = ((size_t)NSEG + 4) * 4;        //    800,016
    const size_t SZ_CUR  = (size_t)NSEG * 4;              //    800,000
    const size_t SZ_CNT  = (size_t)NSEG * 4;              //    800,000
    const size_t SZ_PART = 4096;
    const size_t TOTAL = SZ_XB + 2 * SZ_ES + SZ_AB + SZ_WT + SZ_WCT +
                         SZ_ESRC + SZ_OFF + SZ_CUR + SZ_CNT + SZ_PART;

    if (ws_size < TOTAL) {
        fill_kernel<<<(out_size + 255) / 256, 256, 0, stream>>>((float*)d_out, out_size);
        return;
    }

    char* ws = (char*)d_ws;
    size_t o = 0;
    bf16*  Xb      = (bf16*)(ws + o);  o += SZ_XB;
    float* es      = (float*)(ws + o); o += SZ_ES;
    float* ed      = (float*)(ws + o); o += SZ_ES;
    bf16*  Ab      = (bf16*)(ws + o);  o += SZ_AB;   // also Gb
    bf16*  Wt      = (bf16*)(ws + o);  o += SZ_WT;
    bf16*  Wct     = (bf16*)(ws + o);  o += SZ_WCT;
    int*   esrc    = (int*)(ws + o);   o += SZ_ESRC;
    int*   offsets = (int*)(ws + o);   o += SZ_OFF;
    int*   cursor  = (int*)(ws + o);   o += SZ_CUR;
    int*   counts  = (int*)(ws + o);   o += SZ_CNT;
    int*   partials= (int*)(ws + o);
    float* S       = (float*)d_out;  // S scratch in d_out; lang_kernel overwrites

    hipMemsetAsync(counts, 0, SZ_CNT, stream);

    conv_node_kernel<<<(NN * 128 + 255) / 256, 256, 0, stream>>>(node_inp, Ab);
    conv_w_kernel<<<(768 * 128 + 255) / 256, 256, 0, stream>>>(W_rel, W_self, W_cross, Wt, Wct);

    dim3 g1((NN + 127) / 128, 5);
    gemm_mfma<0><<<g1, 256, 0, stream>>>(Ab, Wt, Xb, S, NN);

    int ne_t = NREL * NN * NHEAD;
    es_ed_kernel<<<(ne_t + 255) / 256, 256, 0, stream>>>(Xb, att_src_rel, att_dst_rel, es, ed);

    // counting sort by (rel,dst)
    hist_kernel<<<(NE + 255) / 256, 256, 0, stream>>>(edge_index, edge_type, counts);
    scan1_kernel<<<NPART, 256, 0, stream>>>(counts, offsets, partials);
    scan2_kernel<<<1, 1024, 0, stream>>>(partials, offsets);
    scan3_kernel<<<NPART, 256, 0, stream>>>(offsets, partials, cursor);
    scatter_kernel<<<(NE + 255) / 256, 256, 0, stream>>>(edge_index, edge_type, cursor, esrc);

    dim3 g2((NN + 127) / 128, 1);
    bf16* Gb = Ab;  // Ab dead after gemm_mfma<0>
    for (int r = 0; r < NREL; ++r) {
        agg_rel_kernel<<<(NN + 3) / 4, 256, 0, stream>>>(esrc, offsets, Xb, es, ed,
                                                         bias_rel, Gb, r);
        gemm_mfma<1><<<g2, 256, 0, stream>>>(Gb, Wct, Xb + (size_t)r * NN * 128, nullptr, NN);
    }

    lang_kernel<<<NN / 2, 256, 0, stream>>>(S, Xb, offsets, att_src_lang, att_dst_lang,
                                            bias_lang, (float*)d_out);
}

// Round 6
// 383.765 us; speedup vs baseline: 3.7833x; 1.1794x over previous
//
#include <hip/hip_runtime.h>
#include <hip/hip_bf16.h>
#include <math.h>

#define NN 50000
#define NE 800000
#define NREL 4
#define NHEAD 8
#define NSEG (NREL * NN)            // 200000 (rel,dst) segments
#define NPART ((NSEG + 255) / 256)  // 782 scan partials

typedef __hip_bfloat16 bf16;
typedef short short8 __attribute__((ext_vector_type(8)));
typedef float floatx4 __attribute__((ext_vector_type(4)));

__device__ __forceinline__ float b2f(bf16 v) { return __bfloat162float(v); }
__device__ __forceinline__ float us2f(unsigned short u) {
    return __uint_as_float(((unsigned)u) << 16);
}

// ---------------------------------------------------------------------------
// Diagnostic: fill out with 1000.0 when ws_size is insufficient
// ---------------------------------------------------------------------------
__global__ void fill_kernel(float* __restrict__ out, int n) {
    int t = blockIdx.x * blockDim.x + threadIdx.x;
    if (t < n) out[t] = 1000.0f;
}

// ---------------------------------------------------------------------------
// Pack weights, transposed to [col][k] bf16 for MFMA B-operand staging.
// ---------------------------------------------------------------------------
__global__ void conv_w_kernel(const float* __restrict__ W_rel,
                              const float* __restrict__ W_self,
                              const float* __restrict__ W_cross,
                              bf16* __restrict__ Wt, bf16* __restrict__ Wct) {
    int t = blockIdx.x * blockDim.x + threadIdx.x;
    if (t < 640 * 128) {
        int col = t >> 7, k = t & 127;
        float v;
        if (col < 512) {
            int r = col >> 7, c = col & 127;
            v = W_rel[(r * 128 + k) * 128 + c];
        } else {
            v = W_self[k * 128 + (col - 512)];
        }
        Wt[t] = __float2bfloat16(v);
    } else if (t < 640 * 128 + 128 * 128) {
        int u = t - 640 * 128;
        int n = u >> 7, k = u & 127;
        Wct[u] = __float2bfloat16(W_cross[k * 128 + n]);
    }
}

// ---------------------------------------------------------------------------
// MFMA GEMM. A is fp32 [M,128] (MODE 0, converted to bf16 during staging)
// or bf16 [M,128] (MODE 1). Bt[Ncols,128] bf16 (B^T, k-contig).
// MODE 0: grid.y=5 -> cols<512 to Xb[4,NN,128] bf16, cols>=512 to S f32
// MODE 1: grid.y=1 -> outb[M,128] bf16
// Block: 256 thr = 4 waves; 128x128 C-tile; wave = 64x64 quadrant (4x4 of 16x16)
// ---------------------------------------------------------------------------
template<int MODE>
__global__ __launch_bounds__(256) void gemm_mfma(
    const void* __restrict__ Ain,
    const bf16* __restrict__ Bt,
    bf16* __restrict__ outb,
    float* __restrict__ outf,
    int M)
{
    __shared__ __align__(16) short As[128][40];
    __shared__ __align__(16) short Bs[128][40];
    const int tid  = threadIdx.x;
    const int wave = tid >> 6, lane = tid & 63;
    const int quad = lane >> 4, l16 = lane & 15;
    const int wq = wave >> 1, wc = wave & 1;
    const int row0 = blockIdx.x * 128;
    const int col0 = blockIdx.y * 128;

    floatx4 acc[4][4];
    #pragma unroll
    for (int i = 0; i < 4; ++i)
        #pragma unroll
        for (int j = 0; j < 4; ++j) acc[i][j] = (floatx4){0.f, 0.f, 0.f, 0.f};

    for (int k0 = 0; k0 < 128; k0 += 32) {
        #pragma unroll
        for (int i = 0; i < 2; ++i) {
            int c = tid * 2 + i;                  // 512 chunks of 8 elems
            int r = c >> 2, off = (c & 3) * 8;
            int gr = row0 + r;
            short8 v = {0, 0, 0, 0, 0, 0, 0, 0};
            if (MODE == 0) {
                if (gr < M) {
                    const float* ap = (const float*)Ain + (((size_t)gr) << 7) + k0 + off;
                    float4 f0 = *(const float4*)ap;
                    float4 f1 = *(const float4*)(ap + 4);
                    bf16 b0 = __float2bfloat16(f0.x), b1 = __float2bfloat16(f0.y);
                    bf16 b2 = __float2bfloat16(f0.z), b3 = __float2bfloat16(f0.w);
                    bf16 b4 = __float2bfloat16(f1.x), b5 = __float2bfloat16(f1.y);
                    bf16 b6 = __float2bfloat16(f1.z), b7 = __float2bfloat16(f1.w);
                    v = (short8){*(short*)&b0, *(short*)&b1, *(short*)&b2, *(short*)&b3,
                                 *(short*)&b4, *(short*)&b5, *(short*)&b6, *(short*)&b7};
                }
            } else {
                if (gr < M)
                    v = *(const short8*)((const bf16*)Ain + (((size_t)gr) << 7) + k0 + off);
            }
            *(short8*)&As[r][off] = v;
            short8 w = *(const short8*)(Bt + (((size_t)(col0 + r)) << 7) + k0 + off);
            *(short8*)&Bs[r][off] = w;
        }
        __syncthreads();

        short8 av[4], bv[4];
        #pragma unroll
        for (int mt = 0; mt < 4; ++mt)
            av[mt] = *(const short8*)&As[wq * 64 + mt * 16 + l16][quad * 8];
        #pragma unroll
        for (int nt = 0; nt < 4; ++nt)
            bv[nt] = *(const short8*)&Bs[wc * 64 + nt * 16 + l16][quad * 8];
        #pragma unroll
        for (int mt = 0; mt < 4; ++mt)
            #pragma unroll
            for (int nt = 0; nt < 4; ++nt)
                acc[mt][nt] = __builtin_amdgcn_mfma_f32_16x16x32_bf16(
                    av[mt], bv[nt], acc[mt][nt], 0, 0, 0);
        __syncthreads();
    }

    #pragma unroll
    for (int mt = 0; mt < 4; ++mt) {
        #pragma unroll
        for (int reg = 0; reg < 4; ++reg) {
            int gr = row0 + wq * 64 + mt * 16 + quad * 4 + reg;
            if (gr >= M) continue;
            #pragma unroll
            for (int nt = 0; nt < 4; ++nt) {
                int gc = col0 + wc * 64 + nt * 16 + l16;
                float v = acc[mt][nt][reg];
                if (MODE == 0) {
                    if (gc < 512) {
                        int r = gc >> 7, c = gc & 127;
                        outb[((size_t)(r * NN + gr) << 7) + c] = __float2bfloat16(v);
                    } else {
                        outf[(((size_t)gr) << 7) + (gc - 512)] = v;
                    }
                } else {
                    outb[(((size_t)gr) << 7) + gc] = __float2bfloat16(v);
                }
            }
        }
    }
}

// ---------------------------------------------------------------------------
// es/ed: per (r,n,h) 16-wide dot, vectorized short8 loads
// ---------------------------------------------------------------------------
__global__ void es_ed_kernel(const bf16* __restrict__ Xb,
                             const float* __restrict__ att_src,
                             const float* __restrict__ att_dst,
                             float* __restrict__ es, float* __restrict__ ed)
{
    int t = blockIdx.x * blockDim.x + threadIdx.x;
    if (t >= NREL * NN * NHEAD) return;
    int h = t & 7;
    int rn = t >> 3;
    int r = rn / NN;
    const short* xp = (const short*)(Xb + ((size_t)rn << 7) + h * 16);
    short8 v0 = *(const short8*)xp;
    short8 v1 = *(const short8*)(xp + 8);
    const float* as = att_src + (r * 8 + h) * 16;
    const float* ad = att_dst + (r * 8 + h) * 16;
    float s = 0.f, d = 0.f;
    #pragma unroll
    for (int i = 0; i < 8; ++i) {
        float x = us2f((unsigned short)v0[i]);
        s += x * as[i];
        d += x * ad[i];
    }
    #pragma unroll
    for (int i = 0; i < 8; ++i) {
        float x = us2f((unsigned short)v1[i]);
        s += x * as[8 + i];
        d += x * ad[8 + i];
    }
    es[t] = s;
    ed[t] = d;
}

// ---------------------------------------------------------------------------
// Counting sort of edges by seg = rel*NN + dst  (histogram / scan / scatter)
// ---------------------------------------------------------------------------
__global__ void hist_kernel(const int* __restrict__ ei, const int* __restrict__ et,
                            int* __restrict__ counts) {
    int e = blockIdx.x * 256 + threadIdx.x;
    if (e >= NE) return;
    int seg = et[e] * NN + ei[NE + e];
    atomicAdd(&counts[seg], 1);
}

__global__ __launch_bounds__(256) void scan1_kernel(const int* __restrict__ counts,
                                                    int* __restrict__ offsets,
                                                    int* __restrict__ partials) {
    __shared__ int sm[256];
    int b = blockIdx.x, t = threadIdx.x, i = b * 256 + t;
    int v = (i < NSEG) ? counts[i] : 0;
    sm[t] = v;
    __syncthreads();
    #pragma unroll
    for (int off = 1; off < 256; off <<= 1) {
        int x = sm[t];
        int y = (t >= off) ? sm[t - off] : 0;
        __syncthreads();
        sm[t] = x + y;
        __syncthreads();
    }
    if (i < NSEG) offsets[i] = sm[t] - v;   // chunk-local exclusive
    if (t == 255) partials[b] = sm[255];
}

__global__ __launch_bounds__(1024) void scan2_kernel(int* __restrict__ partials,
                                                     int* __restrict__ offsets) {
    __shared__ int sm[1024];
    int t = threadIdx.x;
    int v = (t < NPART) ? partials[t] : 0;
    sm[t] = v;
    __syncthreads();
    #pragma unroll
    for (int off = 1; off < 1024; off <<= 1) {
        int x = sm[t];
        int y = (t >= off) ? sm[t - off] : 0;
        __syncthreads();
        sm[t] = x + y;
        __syncthreads();
    }
    if (t < NPART) partials[t] = sm[t] - v;  // exclusive partial prefix
    if (t == 0) offsets[NSEG] = NE;
}

__global__ __launch_bounds__(256) void scan3_kernel(int* __restrict__ offsets,
                                                    const int* __restrict__ partials,
                                                    int* __restrict__ cursor) {
    int b = blockIdx.x, i = b * 256 + threadIdx.x;
    if (i >= NSEG) return;
    int v = offsets[i] + partials[b];
    offsets[i] = v;
    cursor[i] = v;
}

__global__ void scatter_kernel(const int* __restrict__ ei, const int* __restrict__ et,
                               int* __restrict__ cursor, int* __restrict__ esrc) {
    int e = blockIdx.x * 256 + threadIdx.x;
    if (e >= NE) return;
    int seg = et[e] * NN + ei[NE + e];
    int pos = atomicAdd(&cursor[seg], 1);
    esrc[pos] = ei[e];
}

// ---------------------------------------------------------------------------
// Batched aggregation: grid.y = rel. 64 lanes per dst node walk its CSR slice,
// 2-edge software pipeline; fused normalize+bias+GELU -> Gb4[(rel*NN+n),128] bf16
// lane l covers features {2l, 2l+1}; head h = l>>3.
// ---------------------------------------------------------------------------
__global__ __launch_bounds__(256) void agg_kernel(
    const int* __restrict__ esrc, const int* __restrict__ offsets,
    const bf16* __restrict__ Xb, const float* __restrict__ es,
    const float* __restrict__ ed, const float* __restrict__ bias_rel,
    bf16* __restrict__ Gb4)
{
    int rel = blockIdx.y;
    int n = blockIdx.x * 4 + (threadIdx.x >> 6);
    if (n >= NN) return;
    int l = threadIdx.x & 63;
    int h = l >> 3;
    int f = l * 2;
    int seg = rel * NN + n;
    int beg = offsets[seg], end = offsets[seg + 1];
    float edv = ed[(size_t)seg * 8 + h];
    float a0 = 0.f, a1 = 0.f, den = 0.f;
    const unsigned short* Xr = (const unsigned short*)(Xb + (((size_t)rel * NN) << 7));
    const float* esr = es + (size_t)(rel * NN) * 8;

    int e = beg;
    for (; e + 1 < end; e += 2) {
        int s0 = esrc[e], s1 = esrc[e + 1];
        float e0 = esr[(size_t)s0 * 8 + h], e1 = esr[(size_t)s1 * 8 + h];
        ushort2 u0 = *(const ushort2*)(Xr + (((size_t)s0) << 7) + f);
        ushort2 u1 = *(const ushort2*)(Xr + (((size_t)s1) << 7) + f);
        float aa0 = e0 + edv, aa1 = e1 + edv;
        float lg0 = aa0 > 0.f ? aa0 : 0.2f * aa0;
        float lg1 = aa1 > 0.f ? aa1 : 0.2f * aa1;
        float w0 = expf(fminf(lg0, 80.f));
        float w1 = expf(fminf(lg1, 80.f));
        a0 += w0 * us2f(u0.x) + w1 * us2f(u1.x);
        a1 += w0 * us2f(u0.y) + w1 * us2f(u1.y);
        den += w0 + w1;
    }
    if (e < end) {
        int s0 = esrc[e];
        float e0 = esr[(size_t)s0 * 8 + h];
        ushort2 u0 = *(const ushort2*)(Xr + (((size_t)s0) << 7) + f);
        float aa0 = e0 + edv;
        float lg0 = aa0 > 0.f ? aa0 : 0.2f * aa0;
        float w0 = expf(fminf(lg0, 80.f));
        a0 += w0 * us2f(u0.x);
        a1 += w0 * us2f(u0.y);
        den += w0;
    }

    float inv = den > 0.f ? 1.f / den : 0.f;
    float v0 = a0 * inv + bias_rel[rel * 128 + f];
    float v1 = a1 * inv + bias_rel[rel * 128 + f + 1];
    v0 = 0.5f * v0 * (1.f + erff(v0 * 0.70710678118654752f));
    v1 = 0.5f * v1 * (1.f + erff(v1 * 0.70710678118654752f));
    bf16 g0 = __float2bfloat16(v0), g1 = __float2bfloat16(v1);
    ushort2 o;
    o.x = *(unsigned short*)&g0;
    o.y = *(unsigned short*)&g1;
    *(ushort2*)((unsigned short*)Gb4 + (((size_t)seg) << 7) + f) = o;
}

// ---------------------------------------------------------------------------
// lang conv: per node 5-way softmax over {S, h0..h3}; S lives in `out`.
// ---------------------------------------------------------------------------
__global__ __launch_bounds__(256) void lang_kernel(
    const float* __restrict__ S, const bf16* __restrict__ Hb,
    const int* __restrict__ offsets,
    const float* __restrict__ att_src_lang, const float* __restrict__ att_dst_lang,
    const float* __restrict__ bias_lang, float* __restrict__ out)
{
    int n = blockIdx.x * 2 + (threadIdx.x >> 7);
    if (n >= NN) return;
    int d = threadIdx.x & 127;
    int h = d >> 4, dd = d & 15;

    float ent[5];
    ent[0] = S[((size_t)n << 7) + d];
    #pragma unroll
    for (int r = 0; r < 4; ++r)
        ent[r + 1] = b2f(Hb[((size_t)(r * NN + n) << 7) + d]);

    float asl = att_src_lang[h * 16 + dd];
    float adl = att_dst_lang[h * 16 + dd];

    float ls[5];
    #pragma unroll
    for (int k = 0; k < 5; ++k) ls[k] = ent[k] * asl;
    float ld = ent[0] * adl;

    #pragma unroll
    for (int off = 1; off < 16; off <<= 1) {
        #pragma unroll
        for (int k = 0; k < 5; ++k) ls[k] += __shfl_xor(ls[k], off);
        ld += __shfl_xor(ld, off);
    }

    bool valid[5];
    valid[0] = true;
    #pragma unroll
    for (int r = 0; r < 4; ++r) {
        int seg = r * NN + n;
        valid[r + 1] = offsets[seg + 1] > offsets[seg];
    }

    float logit[5], m = -1e30f;
    #pragma unroll
    for (int k = 0; k < 5; ++k) {
        float a = ls[k] + ld;
        float l = a > 0.f ? a : 0.2f * a;
        logit[k] = l;
        if (valid[k] && l > m) m = l;
    }
    float sum = 0.f, e[5];
    #pragma unroll
    for (int k = 0; k < 5; ++k) {
        e[k] = valid[k] ? expf(logit[k] - m) : 0.f;
        sum += e[k];
    }
    float o = 0.f;
    #pragma unroll
    for (int k = 0; k < 5; ++k) o += e[k] * ent[k];
    o = o / sum + bias_lang[d];
    out[((size_t)n << 7) + d] = o;
}

// ---------------------------------------------------------------------------
extern "C" void kernel_launch(void* const* d_in, const int* in_sizes, int n_in,
                              void* d_out, int out_size, void* d_ws, size_t ws_size,
                              hipStream_t stream) {
    const float* node_inp     = (const float*)d_in[0];
    const int*   edge_index   = (const int*)d_in[1];
    const int*   edge_type    = (const int*)d_in[2];
    const float* W_rel        = (const float*)d_in[3];
    const float* att_src_rel  = (const float*)d_in[4];
    const float* att_dst_rel  = (const float*)d_in[5];
    const float* bias_rel     = (const float*)d_in[6];
    const float* W_self       = (const float*)d_in[7];
    const float* W_cross      = (const float*)d_in[8];
    const float* att_src_lang = (const float*)d_in[9];
    const float* att_dst_lang = (const float*)d_in[10];
    const float* bias_lang    = (const float*)d_in[11];
    (void)in_sizes; (void)n_in;

    // workspace layout (bytes) — total ~120.2 MB (<121.6 MB proven in R3)
    const size_t SZ_XB   = (size_t)NREL * NN * 128 * 2;   // 51,200,000 (bf16)
    const size_t SZ_ES   = (size_t)NREL * NN * 8 * 4;     //  6,400,000
    const size_t SZ_GB4  = (size_t)NREL * NN * 128 * 2;   // 51,200,000 (bf16)
    const size_t SZ_WT   = 640 * 128 * 2;                 //    163,840
    const size_t SZ_WCT  = 128 * 128 * 2;                 //     32,768
    const size_t SZ_ESRC = (size_t)NE * 4;                //  3,200,000
    const size_t SZ_OFF  = ((size_t)NSEG + 4) * 4;        //    800,016
    const size_t SZ_CNT  = (size_t)NSEG * 4;              //    800,000 (counts, reused as cursor)
    const size_t SZ_PART = 4096;
    const size_t TOTAL = SZ_XB + 2 * SZ_ES + SZ_GB4 + SZ_WT + SZ_WCT +
                         SZ_ESRC + SZ_OFF + SZ_CNT + SZ_PART;

    if (ws_size < TOTAL) {
        fill_kernel<<<(out_size + 255) / 256, 256, 0, stream>>>((float*)d_out, out_size);
        return;
    }

    char* ws = (char*)d_ws;
    size_t o = 0;
    bf16*  Xb      = (bf16*)(ws + o);  o += SZ_XB;
    float* es      = (float*)(ws + o); o += SZ_ES;
    float* ed      = (float*)(ws + o); o += SZ_ES;
    bf16*  Gb4     = (bf16*)(ws + o);  o += SZ_GB4;
    bf16*  Wt      = (bf16*)(ws + o);  o += SZ_WT;
    bf16*  Wct     = (bf16*)(ws + o);  o += SZ_WCT;
    int*   esrc    = (int*)(ws + o);   o += SZ_ESRC;
    int*   offsets = (int*)(ws + o);   o += SZ_OFF;
    int*   counts  = (int*)(ws + o);   o += SZ_CNT;   // reused as cursor in scan3/scatter
    int*   partials= (int*)(ws + o);
    float* S       = (float*)d_out;  // S scratch in d_out; lang_kernel overwrites

    hipMemsetAsync(counts, 0, SZ_CNT, stream);

    conv_w_kernel<<<(768 * 128 + 255) / 256, 256, 0, stream>>>(W_rel, W_self, W_cross, Wt, Wct);

    dim3 g1((NN + 127) / 128, 5);
    gemm_mfma<0><<<g1, 256, 0, stream>>>(node_inp, Wt, Xb, S, NN);

    int ne_t = NREL * NN * NHEAD;
    es_ed_kernel<<<(ne_t + 255) / 256, 256, 0, stream>>>(Xb, att_src_rel, att_dst_rel, es, ed);

    // counting sort by (rel,dst)
    hist_kernel<<<(NE + 255) / 256, 256, 0, stream>>>(edge_index, edge_type, counts);
    scan1_kernel<<<NPART, 256, 0, stream>>>(counts, offsets, partials);
    scan2_kernel<<<1, 1024, 0, stream>>>(partials, offsets);
    scan3_kernel<<<NPART, 256, 0, stream>>>(offsets, partials, counts);
    scatter_kernel<<<(NE + 255) / 256, 256, 0, stream>>>(edge_index, edge_type, counts, esrc);

    // batched aggregation over all relations
    dim3 ga((NN + 3) / 4, NREL);
    agg_kernel<<<ga, 256, 0, stream>>>(esrc, offsets, Xb, es, ed, bias_rel, Gb4);

    // batched cross-GEMM: [4*NN,128] @ Wct -> Hb (overwrites Xb)
    dim3 g2((NREL * NN + 127) / 128, 1);
    gemm_mfma<1><<<g2, 256, 0, stream>>>(Gb4, Wct, Xb, nullptr, NREL * NN);

    lang_kernel<<<NN / 2, 256, 0, stream>>>(S, Xb, offsets, att_src_lang, att_dst_lang,
                                            bias_lang, (float*)d_out);
}

// Round 7
// 370.926 us; speedup vs baseline: 3.9142x; 1.0346x over previous
//
#include <hip/hip_runtime.h>
#include <hip/hip_bf16.h>
#include <math.h>

#define NN 50000
#define NE 800000
#define NREL 4
#define NHEAD 8
#define NSEG (NREL * NN)            // 200000 (rel,dst) segments
#define NPART ((NSEG + 255) / 256)  // 782 scan partials

typedef __hip_bfloat16 bf16;
typedef short short8 __attribute__((ext_vector_type(8)));
typedef float floatx4 __attribute__((ext_vector_type(4)));

__device__ __forceinline__ float b2f(bf16 v) { return __bfloat162float(v); }
__device__ __forceinline__ float us2f(unsigned short u) {
    return __uint_as_float(((unsigned)u) << 16);
}

// ---------------------------------------------------------------------------
// Diagnostic: fill out with 1000.0 when ws_size is insufficient
// ---------------------------------------------------------------------------
__global__ void fill_kernel(float* __restrict__ out, int n) {
    int t = blockIdx.x * blockDim.x + threadIdx.x;
    if (t < n) out[t] = 1000.0f;
}

// ---------------------------------------------------------------------------
// Pack weights transposed to [outcol][k] bf16.
// Wt[768][128]: rows 0..511 W_rel, 512..639 W_self,
//               640..671 es-vectors (W_r @ a_src), 672..703 ed-vectors,
//               704..767 zero padding.
// Wct[128][128]: W_cross transposed.
// ---------------------------------------------------------------------------
__global__ void conv_w_kernel(const float* __restrict__ W_rel,
                              const float* __restrict__ W_self,
                              const float* __restrict__ W_cross,
                              const float* __restrict__ a_src,
                              const float* __restrict__ a_dst,
                              bf16* __restrict__ Wt, bf16* __restrict__ Wct) {
    int t = blockIdx.x * blockDim.x + threadIdx.x;
    if (t < 768 * 128) {
        int row = t >> 7, k = t & 127;
        float v;
        if (row < 512) {
            int r = row >> 7, c = row & 127;
            v = W_rel[(r * 128 + k) * 128 + c];
        } else if (row < 640) {
            v = W_self[k * 128 + (row - 512)];
        } else if (row < 704) {
            int q = row - 640;
            bool is_src = q < 32;
            int qq = is_src ? q : q - 32;
            int r = qq >> 3, h = qq & 7;
            const float* av = (is_src ? a_src : a_dst) + (r * 8 + h) * 16;
            const float* wr = W_rel + (size_t)(r * 128 + k) * 128 + h * 16;
            float s = 0.f;
            #pragma unroll
            for (int dd = 0; dd < 16; ++dd) s += wr[dd] * av[dd];
            v = s;
        } else {
            v = 0.f;
        }
        Wt[t] = __float2bfloat16(v);
    } else if (t < 768 * 128 + 128 * 128) {
        int u = t - 768 * 128;
        int n = u >> 7, k = u & 127;
        Wct[u] = __float2bfloat16(W_cross[k * 128 + n]);
    }
}

// ---------------------------------------------------------------------------
// MFMA GEMM. A fp32 [M,128] (MODE 0, converted during staging) or bf16 (MODE 1).
// Bt[Ncols,128] bf16 (B^T, k-contig).
// MODE 0 (grid.y=6): y<4 -> Xb[y,:,:] bf16 (coalesced via LDS transpose);
//                    y=4 -> S f32; y=5 -> es/ed f32 (scattered, small).
// MODE 1 (grid.y=1): outb[M,128] bf16.
// ---------------------------------------------------------------------------
template<int MODE>
__global__ __launch_bounds__(256) void gemm_mfma(
    const void* __restrict__ Ain,
    const bf16* __restrict__ Bt,
    bf16* __restrict__ outb,
    float* __restrict__ outf,
    float* __restrict__ es,
    float* __restrict__ ed,
    int M)
{
    __shared__ __align__(16) char smem[20480];
    short (*As)[40] = (short (*)[40])smem;
    short (*Bs)[40] = (short (*)[40])(smem + 10240);

    const int tid  = threadIdx.x;
    const int wave = tid >> 6, lane = tid & 63;
    const int quad = lane >> 4, l16 = lane & 15;
    const int wq = wave >> 1, wc = wave & 1;
    const int row0 = blockIdx.x * 128;
    const int col0 = blockIdx.y * 128;

    floatx4 acc[4][4];
    #pragma unroll
    for (int i = 0; i < 4; ++i)
        #pragma unroll
        for (int j = 0; j < 4; ++j) acc[i][j] = (floatx4){0.f, 0.f, 0.f, 0.f};

    for (int k0 = 0; k0 < 128; k0 += 32) {
        #pragma unroll
        for (int i = 0; i < 2; ++i) {
            int c = tid * 2 + i;                  // 512 chunks of 8 elems
            int r = c >> 2, off = (c & 3) * 8;
            int gr = row0 + r;
            short8 v = {0, 0, 0, 0, 0, 0, 0, 0};
            if (MODE == 0) {
                if (gr < M) {
                    const float* ap = (const float*)Ain + (((size_t)gr) << 7) + k0 + off;
                    float4 f0 = *(const float4*)ap;
                    float4 f1 = *(const float4*)(ap + 4);
                    bf16 b0 = __float2bfloat16(f0.x), b1 = __float2bfloat16(f0.y);
                    bf16 b2 = __float2bfloat16(f0.z), b3 = __float2bfloat16(f0.w);
                    bf16 b4 = __float2bfloat16(f1.x), b5 = __float2bfloat16(f1.y);
                    bf16 b6 = __float2bfloat16(f1.z), b7 = __float2bfloat16(f1.w);
                    v = (short8){*(short*)&b0, *(short*)&b1, *(short*)&b2, *(short*)&b3,
                                 *(short*)&b4, *(short*)&b5, *(short*)&b6, *(short*)&b7};
                }
            } else {
                if (gr < M)
                    v = *(const short8*)((const bf16*)Ain + (((size_t)gr) << 7) + k0 + off);
            }
            *(short8*)&As[r][off] = v;
            short8 w = *(const short8*)(Bt + (((size_t)(col0 + r)) << 7) + k0 + off);
            *(short8*)&Bs[r][off] = w;
        }
        __syncthreads();

        short8 av[4], bv[4];
        #pragma unroll
        for (int mt = 0; mt < 4; ++mt)
            av[mt] = *(const short8*)&As[wq * 64 + mt * 16 + l16][quad * 8];
        #pragma unroll
        for (int nt = 0; nt < 4; ++nt)
            bv[nt] = *(const short8*)&Bs[wc * 64 + nt * 16 + l16][quad * 8];
        #pragma unroll
        for (int mt = 0; mt < 4; ++mt)
            #pragma unroll
            for (int nt = 0; nt < 4; ++nt)
                acc[mt][nt] = __builtin_amdgcn_mfma_f32_16x16x32_bf16(
                    av[mt], bv[nt], acc[mt][nt], 0, 0, 0);
        __syncthreads();
    }

    // ---------------- epilogue ----------------
    if (MODE == 0 && blockIdx.y == 5) {
        // es/ed columns: gc = 640 + wc*64 + nt*16 + l16; wc==1 -> padding, skip
        if (wc == 0) {
            #pragma unroll
            for (int mt = 0; mt < 4; ++mt) {
                #pragma unroll
                for (int reg = 0; reg < 4; ++reg) {
                    int gr = row0 + wq * 64 + mt * 16 + quad * 4 + reg;
                    if (gr >= M) continue;
                    #pragma unroll
                    for (int nt = 0; nt < 4; ++nt) {
                        int q = nt * 16 + l16;          // 0..63
                        float v = acc[mt][nt][reg];
                        if (q < 32)
                            es[(size_t)((q >> 3) * NN + gr) * 8 + (q & 7)] = v;
                        else
                            ed[(size_t)(((q - 32) >> 3) * NN + gr) * 8 + ((q - 32) & 7)] = v;
                    }
                }
            }
        }
        return;
    }

    // LDS-transpose path: wave-private [16][68] f32 region
    float* ct = (float*)(smem + wave * 5120);
    const int rr2 = lane >> 2;
    const int cc0 = (lane & 3) * 16;

    for (int mt = 0; mt < 4; ++mt) {
        #pragma unroll
        for (int nt = 0; nt < 4; ++nt)
            #pragma unroll
            for (int reg = 0; reg < 4; ++reg)
                ct[(quad * 4 + reg) * 68 + nt * 16 + l16] = acc[mt][nt][reg];
        __syncthreads();

        int gr2 = row0 + wq * 64 + mt * 16 + rr2;
        if (gr2 < M) {
            float4 f0 = *(const float4*)&ct[rr2 * 68 + cc0];
            float4 f1 = *(const float4*)&ct[rr2 * 68 + cc0 + 4];
            float4 f2 = *(const float4*)&ct[rr2 * 68 + cc0 + 8];
            float4 f3 = *(const float4*)&ct[rr2 * 68 + cc0 + 12];
            int cb = wc * 64 + cc0;
            if (MODE == 0 && blockIdx.y == 4) {
                float* dst = outf + (((size_t)gr2) << 7) + cb;
                ((float4*)dst)[0] = f0;
                ((float4*)dst)[1] = f1;
                ((float4*)dst)[2] = f2;
                ((float4*)dst)[3] = f3;
            } else {
                float tmp[16] = {f0.x, f0.y, f0.z, f0.w, f1.x, f1.y, f1.z, f1.w,
                                 f2.x, f2.y, f2.z, f2.w, f3.x, f3.y, f3.z, f3.w};
                short8 o0, o1;
                #pragma unroll
                for (int j = 0; j < 8; ++j) {
                    bf16 b = __float2bfloat16(tmp[j]);
                    o0[j] = *(short*)&b;
                }
                #pragma unroll
                for (int j = 0; j < 8; ++j) {
                    bf16 b = __float2bfloat16(tmp[8 + j]);
                    o1[j] = *(short*)&b;
                }
                bf16* dst;
                if (MODE == 0)
                    dst = outb + ((size_t)(blockIdx.y * NN + gr2) << 7) + cb;
                else
                    dst = outb + (((size_t)gr2) << 7) + cb;
                *(short8*)dst = o0;
                *(short8*)(dst + 8) = o1;
            }
        }
        __syncthreads();
    }
}

// ---------------------------------------------------------------------------
// Counting sort of edges by seg = rel*NN + dst  (histogram / scan / scatter)
// ---------------------------------------------------------------------------
__global__ void hist_kernel(const int* __restrict__ ei, const int* __restrict__ et,
                            int* __restrict__ counts) {
    int e = blockIdx.x * 256 + threadIdx.x;
    if (e >= NE) return;
    int seg = et[e] * NN + ei[NE + e];
    atomicAdd(&counts[seg], 1);
}

__global__ __launch_bounds__(256) void scan1_kernel(const int* __restrict__ counts,
                                                    int* __restrict__ offsets,
                                                    int* __restrict__ partials) {
    __shared__ int sm[256];
    int b = blockIdx.x, t = threadIdx.x, i = b * 256 + t;
    int v = (i < NSEG) ? counts[i] : 0;
    sm[t] = v;
    __syncthreads();
    #pragma unroll
    for (int off = 1; off < 256; off <<= 1) {
        int x = sm[t];
        int y = (t >= off) ? sm[t - off] : 0;
        __syncthreads();
        sm[t] = x + y;
        __syncthreads();
    }
    if (i < NSEG) offsets[i] = sm[t] - v;   // chunk-local exclusive
    if (t == 255) partials[b] = sm[255];
}

__global__ __launch_bounds__(1024) void scan2_kernel(int* __restrict__ partials,
                                                     int* __restrict__ offsets) {
    __shared__ int sm[1024];
    int t = threadIdx.x;
    int v = (t < NPART) ? partials[t] : 0;
    sm[t] = v;
    __syncthreads();
    #pragma unroll
    for (int off = 1; off < 1024; off <<= 1) {
        int x = sm[t];
        int y = (t >= off) ? sm[t - off] : 0;
        __syncthreads();
        sm[t] = x + y;
        __syncthreads();
    }
    if (t < NPART) partials[t] = sm[t] - v;  // exclusive partial prefix
    if (t == 0) offsets[NSEG] = NE;
}

__global__ __launch_bounds__(256) void scan3_kernel(int* __restrict__ offsets,
                                                    const int* __restrict__ partials,
                                                    int* __restrict__ cursor) {
    int b = blockIdx.x, i = b * 256 + threadIdx.x;
    if (i >= NSEG) return;
    int v = offsets[i] + partials[b];
    offsets[i] = v;
    cursor[i] = v;
}

__global__ void scatter_kernel(const int* __restrict__ ei, const int* __restrict__ et,
                               int* __restrict__ cursor, int* __restrict__ esrc) {
    int e = blockIdx.x * 256 + threadIdx.x;
    if (e >= NE) return;
    int seg = et[e] * NN + ei[NE + e];
    int pos = atomicAdd(&cursor[seg], 1);
    esrc[pos] = ei[e];
}

// ---------------------------------------------------------------------------
// Batched aggregation: grid.y = rel. 64 lanes per dst node walk its CSR slice,
// 2-edge software pipeline, fast exp; fused normalize+bias+GELU -> Gb4 bf16.
// lane l covers features {2l, 2l+1}; head h = l>>3.
// ---------------------------------------------------------------------------
__global__ __launch_bounds__(256) void agg_kernel(
    const int* __restrict__ esrc, const int* __restrict__ offsets,
    const bf16* __restrict__ Xb, const float* __restrict__ es,
    const float* __restrict__ ed, const float* __restrict__ bias_rel,
    bf16* __restrict__ Gb4)
{
    int rel = blockIdx.y;
    int n = blockIdx.x * 4 + (threadIdx.x >> 6);
    if (n >= NN) return;
    int l = threadIdx.x & 63;
    int h = l >> 3;
    int f = l * 2;
    int seg = rel * NN + n;
    int beg = offsets[seg], end = offsets[seg + 1];
    float edv = ed[(size_t)seg * 8 + h];
    float a0 = 0.f, a1 = 0.f, den = 0.f;
    const unsigned short* Xr = (const unsigned short*)(Xb + (((size_t)rel * NN) << 7));
    const float* esr = es + (size_t)(rel * NN) * 8;

    int e = beg;
    for (; e + 1 < end; e += 2) {
        int s0 = esrc[e], s1 = esrc[e + 1];
        float e0 = esr[(size_t)s0 * 8 + h], e1 = esr[(size_t)s1 * 8 + h];
        ushort2 u0 = *(const ushort2*)(Xr + (((size_t)s0) << 7) + f);
        ushort2 u1 = *(const ushort2*)(Xr + (((size_t)s1) << 7) + f);
        float aa0 = e0 + edv, aa1 = e1 + edv;
        float lg0 = aa0 > 0.f ? aa0 : 0.2f * aa0;
        float lg1 = aa1 > 0.f ? aa1 : 0.2f * aa1;
        float w0 = __expf(fminf(lg0, 80.f));
        float w1 = __expf(fminf(lg1, 80.f));
        a0 += w0 * us2f(u0.x) + w1 * us2f(u1.x);
        a1 += w0 * us2f(u0.y) + w1 * us2f(u1.y);
        den += w0 + w1;
    }
    if (e < end) {
        int s0 = esrc[e];
        float e0 = esr[(size_t)s0 * 8 + h];
        ushort2 u0 = *(const ushort2*)(Xr + (((size_t)s0) << 7) + f);
        float aa0 = e0 + edv;
        float lg0 = aa0 > 0.f ? aa0 : 0.2f * aa0;
        float w0 = __expf(fminf(lg0, 80.f));
        a0 += w0 * us2f(u0.x);
        a1 += w0 * us2f(u0.y);
        den += w0;
    }

    float inv = den > 0.f ? 1.f / den : 0.f;
    float v0 = a0 * inv + bias_rel[rel * 128 + f];
    float v1 = a1 * inv + bias_rel[rel * 128 + f + 1];
    v0 = 0.5f * v0 * (1.f + erff(v0 * 0.70710678118654752f));
    v1 = 0.5f * v1 * (1.f + erff(v1 * 0.70710678118654752f));
    bf16 g0 = __float2bfloat16(v0), g1 = __float2bfloat16(v1);
    ushort2 o;
    o.x = *(unsigned short*)&g0;
    o.y = *(unsigned short*)&g1;
    *(ushort2*)((unsigned short*)Gb4 + (((size_t)seg) << 7) + f) = o;
}

// ---------------------------------------------------------------------------
// lang conv: per node 5-way softmax over {S, h0..h3}; S lives in `out`.
// ---------------------------------------------------------------------------
__global__ __launch_bounds__(256) void lang_kernel(
    const float* __restrict__ S, const bf16* __restrict__ Hb,
    const int* __restrict__ offsets,
    const float* __restrict__ att_src_lang, const float* __restrict__ att_dst_lang,
    const float* __restrict__ bias_lang, float* __restrict__ out)
{
    int n = blockIdx.x * 2 + (threadIdx.x >> 7);
    if (n >= NN) return;
    int d = threadIdx.x & 127;
    int h = d >> 4, dd = d & 15;

    float ent[5];
    ent[0] = S[((size_t)n << 7) + d];
    #pragma unroll
    for (int r = 0; r < 4; ++r)
        ent[r + 1] = b2f(Hb[((size_t)(r * NN + n) << 7) + d]);

    float asl = att_src_lang[h * 16 + dd];
    float adl = att_dst_lang[h * 16 + dd];

    float ls[5];
    #pragma unroll
    for (int k = 0; k < 5; ++k) ls[k] = ent[k] * asl;
    float ld = ent[0] * adl;

    #pragma unroll
    for (int off = 1; off < 16; off <<= 1) {
        #pragma unroll
        for (int k = 0; k < 5; ++k) ls[k] += __shfl_xor(ls[k], off);
        ld += __shfl_xor(ld, off);
    }

    bool valid[5];
    valid[0] = true;
    #pragma unroll
    for (int r = 0; r < 4; ++r) {
        int seg = r * NN + n;
        valid[r + 1] = offsets[seg + 1] > offsets[seg];
    }

    float logit[5], m = -1e30f;
    #pragma unroll
    for (int k = 0; k < 5; ++k) {
        float a = ls[k] + ld;
        float l = a > 0.f ? a : 0.2f * a;
        logit[k] = l;
        if (valid[k] && l > m) m = l;
    }
    float sum = 0.f, e[5];
    #pragma unroll
    for (int k = 0; k < 5; ++k) {
        e[k] = valid[k] ? __expf(logit[k] - m) : 0.f;
        sum += e[k];
    }
    float o = 0.f;
    #pragma unroll
    for (int k = 0; k < 5; ++k) o += e[k] * ent[k];
    o = o / sum + bias_lang[d];
    out[((size_t)n << 7) + d] = o;
}

// ---------------------------------------------------------------------------
extern "C" void kernel_launch(void* const* d_in, const int* in_sizes, int n_in,
                              void* d_out, int out_size, void* d_ws, size_t ws_size,
                              hipStream_t stream) {
    const float* node_inp     = (const float*)d_in[0];
    const int*   edge_index   = (const int*)d_in[1];
    const int*   edge_type    = (const int*)d_in[2];
    const float* W_rel        = (const float*)d_in[3];
    const float* att_src_rel  = (const float*)d_in[4];
    const float* att_dst_rel  = (const float*)d_in[5];
    const float* bias_rel     = (const float*)d_in[6];
    const float* W_self       = (const float*)d_in[7];
    const float* W_cross      = (const float*)d_in[8];
    const float* att_src_lang = (const float*)d_in[9];
    const float* att_dst_lang = (const float*)d_in[10];
    const float* bias_lang    = (const float*)d_in[11];
    (void)in_sizes; (void)n_in;

    // workspace layout (bytes) — total ~120.3 MB (<121.6 MB proven)
    const size_t SZ_XB   = (size_t)NREL * NN * 128 * 2;   // 51,200,000 (bf16)
    const size_t SZ_ES   = (size_t)NREL * NN * 8 * 4;     //  6,400,000
    const size_t SZ_GB4  = (size_t)NREL * NN * 128 * 2;   // 51,200,000 (bf16)
    const size_t SZ_WT   = 768 * 128 * 2;                 //    196,608
    const size_t SZ_WCT  = 128 * 128 * 2;                 //     32,768
    const size_t SZ_ESRC = (size_t)NE * 4;                //  3,200,000
    const size_t SZ_OFF  = ((size_t)NSEG + 4) * 4;        //    800,016
    const size_t SZ_CNT  = (size_t)NSEG * 4;              //    800,000 (counts/cursor)
    const size_t SZ_PART = 4096;
    const size_t TOTAL = SZ_XB + 2 * SZ_ES + SZ_GB4 + SZ_WT + SZ_WCT +
                         SZ_ESRC + SZ_OFF + SZ_CNT + SZ_PART;

    if (ws_size < TOTAL) {
        fill_kernel<<<(out_size + 255) / 256, 256, 0, stream>>>((float*)d_out, out_size);
        return;
    }

    char* ws = (char*)d_ws;
    size_t o = 0;
    bf16*  Xb      = (bf16*)(ws + o);  o += SZ_XB;
    float* es      = (float*)(ws + o); o += SZ_ES;
    float* ed      = (float*)(ws + o); o += SZ_ES;
    bf16*  Gb4     = (bf16*)(ws + o);  o += SZ_GB4;
    bf16*  Wt      = (bf16*)(ws + o);  o += SZ_WT;
    bf16*  Wct     = (bf16*)(ws + o);  o += SZ_WCT;
    int*   esrc    = (int*)(ws + o);   o += SZ_ESRC;
    int*   offsets = (int*)(ws + o);   o += SZ_OFF;
    int*   counts  = (int*)(ws + o);   o += SZ_CNT;   // reused as cursor
    int*   partials= (int*)(ws + o);
    float* S       = (float*)d_out;  // S scratch in d_out; lang_kernel overwrites

    hipMemsetAsync(counts, 0, SZ_CNT, stream);

    conv_w_kernel<<<(768 * 128 + 128 * 128 + 255) / 256, 256, 0, stream>>>(
        W_rel, W_self, W_cross, att_src_rel, att_dst_rel, Wt, Wct);

    // fused GEMM: Xb (4 relations), S, es, ed in one pass
    dim3 g1((NN + 127) / 128, 6);
    gemm_mfma<0><<<g1, 256, 0, stream>>>(node_inp, Wt, Xb, S, es, ed, NN);

    // counting sort by (rel,dst)
    hist_kernel<<<(NE + 255) / 256, 256, 0, stream>>>(edge_index, edge_type, counts);
    scan1_kernel<<<NPART, 256, 0, stream>>>(counts, offsets, partials);
    scan2_kernel<<<1, 1024, 0, stream>>>(partials, offsets);
    scan3_kernel<<<NPART, 256, 0, stream>>>(offsets, partials, counts);
    scatter_kernel<<<(NE + 255) / 256, 256, 0, stream>>>(edge_index, edge_type, counts, esrc);

    // batched aggregation over all relations
    dim3 ga((NN + 3) / 4, NREL);
    agg_kernel<<<ga, 256, 0, stream>>>(esrc, offsets, Xb, es, ed, bias_rel, Gb4);

    // batched cross-GEMM: [4*NN,128] @ Wct -> Hb (overwrites Xb)
    dim3 g2((NREL * NN + 127) / 128, 1);
    gemm_mfma<1><<<g2, 256, 0, stream>>>(Gb4, Wct, Xb, nullptr, nullptr, nullptr, NREL * NN);

    lang_kernel<<<NN / 2, 256, 0, stream>>>(S, Xb, offsets, att_src_lang, att_dst_lang,
                                            bias_lang, (float*)d_out);
}

// Round 8
// 358.571 us; speedup vs baseline: 4.0491x; 1.0345x over previous
//
#include <hip/hip_runtime.h>
#include <hip/hip_bf16.h>
#include <math.h>

#define NN 50000
#define NE 800000
#define NREL 4
#define NHEAD 8
#define NSEG (NREL * NN)            // 200000 (rel,dst) segments
#define NPART ((NSEG + 255) / 256)  // 782 scan partials

typedef __hip_bfloat16 bf16;
typedef short short8 __attribute__((ext_vector_type(8)));
typedef float floatx4 __attribute__((ext_vector_type(4)));

__device__ __forceinline__ float b2f(bf16 v) { return __bfloat162float(v); }
__device__ __forceinline__ float us2f(unsigned short u) {
    return __uint_as_float(((unsigned)u) << 16);
}

// ---------------------------------------------------------------------------
// Diagnostic: fill out with 1000.0 when ws_size is insufficient
// ---------------------------------------------------------------------------
__global__ void fill_kernel(float* __restrict__ out, int n) {
    int t = blockIdx.x * blockDim.x + threadIdx.x;
    if (t < n) out[t] = 1000.0f;
}

// ---------------------------------------------------------------------------
// Pack weights transposed to [outcol][k] bf16.
// Wt[768][128]: rows 0..511 W_rel, 512..639 W_self,
//               640..671 es-vectors (W_r @ a_src), 672..703 ed-vectors,
//               704..767 zero padding.
// Wct[128][128]: W_cross transposed.
// ---------------------------------------------------------------------------
__global__ void conv_w_kernel(const float* __restrict__ W_rel,
                              const float* __restrict__ W_self,
                              const float* __restrict__ W_cross,
                              const float* __restrict__ a_src,
                              const float* __restrict__ a_dst,
                              bf16* __restrict__ Wt, bf16* __restrict__ Wct) {
    int t = blockIdx.x * blockDim.x + threadIdx.x;
    if (t < 768 * 128) {
        int row = t >> 7, k = t & 127;
        float v;
        if (row < 512) {
            int r = row >> 7, c = row & 127;
            v = W_rel[(r * 128 + k) * 128 + c];
        } else if (row < 640) {
            v = W_self[k * 128 + (row - 512)];
        } else if (row < 704) {
            int q = row - 640;
            bool is_src = q < 32;
            int qq = is_src ? q : q - 32;
            int r = qq >> 3, h = qq & 7;
            const float* av = (is_src ? a_src : a_dst) + (r * 8 + h) * 16;
            const float* wr = W_rel + (size_t)(r * 128 + k) * 128 + h * 16;
            float s = 0.f;
            #pragma unroll
            for (int dd = 0; dd < 16; ++dd) s += wr[dd] * av[dd];
            v = s;
        } else {
            v = 0.f;
        }
        Wt[t] = __float2bfloat16(v);
    } else if (t < 768 * 128 + 128 * 128) {
        int u = t - 768 * 128;
        int n = u >> 7, k = u & 127;
        Wct[u] = __float2bfloat16(W_cross[k * 128 + n]);
    }
}

// ---------------------------------------------------------------------------
// MFMA GEMM. A fp32 [M,128] (MODE 0, converted during staging) or bf16 (MODE 1).
// Bt[Ncols,128] bf16 (B^T, k-contig).
// MODE 0 (grid.y=6): y<4 -> Xb[y,:,:] bf16 (coalesced via LDS transpose);
//                    y=4 -> S f32; y=5 -> es/ed f32 (scattered, small).
// MODE 1 (grid.y=1): outb[M,128] bf16.
// ---------------------------------------------------------------------------
template<int MODE>
__global__ __launch_bounds__(256) void gemm_mfma(
    const void* __restrict__ Ain,
    const bf16* __restrict__ Bt,
    bf16* __restrict__ outb,
    float* __restrict__ outf,
    float* __restrict__ es,
    float* __restrict__ ed,
    int M)
{
    __shared__ __align__(16) char smem[20480];
    short (*As)[40] = (short (*)[40])smem;
    short (*Bs)[40] = (short (*)[40])(smem + 10240);

    const int tid  = threadIdx.x;
    const int wave = tid >> 6, lane = tid & 63;
    const int quad = lane >> 4, l16 = lane & 15;
    const int wq = wave >> 1, wc = wave & 1;
    const int row0 = blockIdx.x * 128;
    const int col0 = blockIdx.y * 128;

    floatx4 acc[4][4];
    #pragma unroll
    for (int i = 0; i < 4; ++i)
        #pragma unroll
        for (int j = 0; j < 4; ++j) acc[i][j] = (floatx4){0.f, 0.f, 0.f, 0.f};

    for (int k0 = 0; k0 < 128; k0 += 32) {
        #pragma unroll
        for (int i = 0; i < 2; ++i) {
            int c = tid * 2 + i;                  // 512 chunks of 8 elems
            int r = c >> 2, off = (c & 3) * 8;
            int gr = row0 + r;
            short8 v = {0, 0, 0, 0, 0, 0, 0, 0};
            if (MODE == 0) {
                if (gr < M) {
                    const float* ap = (const float*)Ain + (((size_t)gr) << 7) + k0 + off;
                    float4 f0 = *(const float4*)ap;
                    float4 f1 = *(const float4*)(ap + 4);
                    bf16 b0 = __float2bfloat16(f0.x), b1 = __float2bfloat16(f0.y);
                    bf16 b2 = __float2bfloat16(f0.z), b3 = __float2bfloat16(f0.w);
                    bf16 b4 = __float2bfloat16(f1.x), b5 = __float2bfloat16(f1.y);
                    bf16 b6 = __float2bfloat16(f1.z), b7 = __float2bfloat16(f1.w);
                    v = (short8){*(short*)&b0, *(short*)&b1, *(short*)&b2, *(short*)&b3,
                                 *(short*)&b4, *(short*)&b5, *(short*)&b6, *(short*)&b7};
                }
            } else {
                if (gr < M)
                    v = *(const short8*)((const bf16*)Ain + (((size_t)gr) << 7) + k0 + off);
            }
            *(short8*)&As[r][off] = v;
            short8 w = *(const short8*)(Bt + (((size_t)(col0 + r)) << 7) + k0 + off);
            *(short8*)&Bs[r][off] = w;
        }
        __syncthreads();

        short8 av[4], bv[4];
        #pragma unroll
        for (int mt = 0; mt < 4; ++mt)
            av[mt] = *(const short8*)&As[wq * 64 + mt * 16 + l16][quad * 8];
        #pragma unroll
        for (int nt = 0; nt < 4; ++nt)
            bv[nt] = *(const short8*)&Bs[wc * 64 + nt * 16 + l16][quad * 8];
        #pragma unroll
        for (int mt = 0; mt < 4; ++mt)
            #pragma unroll
            for (int nt = 0; nt < 4; ++nt)
                acc[mt][nt] = __builtin_amdgcn_mfma_f32_16x16x32_bf16(
                    av[mt], bv[nt], acc[mt][nt], 0, 0, 0);
        __syncthreads();
    }

    // ---------------- epilogue ----------------
    if (MODE == 0 && blockIdx.y == 5) {
        // es/ed columns: gc = 640 + wc*64 + nt*16 + l16; wc==1 -> padding, skip
        if (wc == 0) {
            #pragma unroll
            for (int mt = 0; mt < 4; ++mt) {
                #pragma unroll
                for (int reg = 0; reg < 4; ++reg) {
                    int gr = row0 + wq * 64 + mt * 16 + quad * 4 + reg;
                    if (gr >= M) continue;
                    #pragma unroll
                    for (int nt = 0; nt < 4; ++nt) {
                        int q = nt * 16 + l16;          // 0..63
                        float v = acc[mt][nt][reg];
                        if (q < 32)
                            es[(size_t)((q >> 3) * NN + gr) * 8 + (q & 7)] = v;
                        else
                            ed[(size_t)(((q - 32) >> 3) * NN + gr) * 8 + ((q - 32) & 7)] = v;
                    }
                }
            }
        }
        return;
    }

    // LDS-transpose path: wave-private [16][68] f32 region
    float* ct = (float*)(smem + wave * 5120);
    const int rr2 = lane >> 2;
    const int cc0 = (lane & 3) * 16;

    for (int mt = 0; mt < 4; ++mt) {
        #pragma unroll
        for (int nt = 0; nt < 4; ++nt)
            #pragma unroll
            for (int reg = 0; reg < 4; ++reg)
                ct[(quad * 4 + reg) * 68 + nt * 16 + l16] = acc[mt][nt][reg];
        __syncthreads();

        int gr2 = row0 + wq * 64 + mt * 16 + rr2;
        if (gr2 < M) {
            float4 f0 = *(const float4*)&ct[rr2 * 68 + cc0];
            float4 f1 = *(const float4*)&ct[rr2 * 68 + cc0 + 4];
            float4 f2 = *(const float4*)&ct[rr2 * 68 + cc0 + 8];
            float4 f3 = *(const float4*)&ct[rr2 * 68 + cc0 + 12];
            int cb = wc * 64 + cc0;
            if (MODE == 0 && blockIdx.y == 4) {
                float* dst = outf + (((size_t)gr2) << 7) + cb;
                ((float4*)dst)[0] = f0;
                ((float4*)dst)[1] = f1;
                ((float4*)dst)[2] = f2;
                ((float4*)dst)[3] = f3;
            } else {
                float tmp[16] = {f0.x, f0.y, f0.z, f0.w, f1.x, f1.y, f1.z, f1.w,
                                 f2.x, f2.y, f2.z, f2.w, f3.x, f3.y, f3.z, f3.w};
                short8 o0, o1;
                #pragma unroll
                for (int j = 0; j < 8; ++j) {
                    bf16 b = __float2bfloat16(tmp[j]);
                    o0[j] = *(short*)&b;
                }
                #pragma unroll
                for (int j = 0; j < 8; ++j) {
                    bf16 b = __float2bfloat16(tmp[8 + j]);
                    o1[j] = *(short*)&b;
                }
                bf16* dst;
                if (MODE == 0)
                    dst = outb + ((size_t)(blockIdx.y * NN + gr2) << 7) + cb;
                else
                    dst = outb + (((size_t)gr2) << 7) + cb;
                *(short8*)dst = o0;
                *(short8*)(dst + 8) = o1;
            }
        }
        __syncthreads();
    }
}

// ---------------------------------------------------------------------------
// Counting sort of edges by seg = rel*NN + dst  (histogram / scan / scatter)
// ---------------------------------------------------------------------------
__global__ void hist_kernel(const int* __restrict__ ei, const int* __restrict__ et,
                            int* __restrict__ counts) {
    int e = blockIdx.x * 256 + threadIdx.x;
    if (e >= NE) return;
    int seg = et[e] * NN + ei[NE + e];
    atomicAdd(&counts[seg], 1);
}

__global__ __launch_bounds__(256) void scan1_kernel(const int* __restrict__ counts,
                                                    int* __restrict__ offsets,
                                                    int* __restrict__ partials) {
    __shared__ int sm[256];
    int b = blockIdx.x, t = threadIdx.x, i = b * 256 + t;
    int v = (i < NSEG) ? counts[i] : 0;
    sm[t] = v;
    __syncthreads();
    #pragma unroll
    for (int off = 1; off < 256; off <<= 1) {
        int x = sm[t];
        int y = (t >= off) ? sm[t - off] : 0;
        __syncthreads();
        sm[t] = x + y;
        __syncthreads();
    }
    if (i < NSEG) offsets[i] = sm[t] - v;   // chunk-local exclusive
    if (t == 255) partials[b] = sm[255];
}

__global__ __launch_bounds__(1024) void scan2_kernel(int* __restrict__ partials,
                                                     int* __restrict__ offsets) {
    __shared__ int sm[1024];
    int t = threadIdx.x;
    int v = (t < NPART) ? partials[t] : 0;
    sm[t] = v;
    __syncthreads();
    #pragma unroll
    for (int off = 1; off < 1024; off <<= 1) {
        int x = sm[t];
        int y = (t >= off) ? sm[t - off] : 0;
        __syncthreads();
        sm[t] = x + y;
        __syncthreads();
    }
    if (t < NPART) partials[t] = sm[t] - v;  // exclusive partial prefix
    if (t == 0) offsets[NSEG] = NE;
}

__global__ __launch_bounds__(256) void scan3_kernel(int* __restrict__ offsets,
                                                    const int* __restrict__ partials,
                                                    int* __restrict__ cursor) {
    int b = blockIdx.x, i = b * 256 + threadIdx.x;
    if (i >= NSEG) return;
    int v = offsets[i] + partials[b];
    offsets[i] = v;
    cursor[i] = v;
}

__global__ void scatter_kernel(const int* __restrict__ ei, const int* __restrict__ et,
                               int* __restrict__ cursor, int* __restrict__ esrc) {
    int e = blockIdx.x * 256 + threadIdx.x;
    if (e >= NE) return;
    int seg = et[e] * NN + ei[NE + e];
    int pos = atomicAdd(&cursor[seg], 1);
    esrc[pos] = ei[e];
}

// ---------------------------------------------------------------------------
// Batched aggregation: grid.y = rel. 64 lanes per dst node walk its CSR slice.
// Scalarized loop: beg/end/esrc wave-uniform (readfirstlane -> SGPR loop,
// s_load of esrc, saddr-form gathers). 32-bit index math only.
// lane l covers features {2l, 2l+1}; head h = l>>3.
// ---------------------------------------------------------------------------
__global__ __launch_bounds__(256) void agg_kernel(
    const int* __restrict__ esrc, const int* __restrict__ offsets,
    const bf16* __restrict__ Xb, const float* __restrict__ es,
    const float* __restrict__ ed, const float* __restrict__ bias_rel,
    bf16* __restrict__ Gb4)
{
    const int rel = blockIdx.y;
    const int n = blockIdx.x * 4 + (threadIdx.x >> 6);
    if (n >= NN) return;
    const int l = threadIdx.x & 63;
    const int h = l >> 3;
    const int f = l * 2;
    const unsigned seg = (unsigned)(rel * NN + n);
    int beg = __builtin_amdgcn_readfirstlane(offsets[seg]);
    int end = __builtin_amdgcn_readfirstlane(offsets[seg + 1]);
    const float edv = ed[seg * 8u + (unsigned)h];
    float a0 = 0.f, a1 = 0.f, den = 0.f;
    const unsigned short* Xr = (const unsigned short*)Xb + (unsigned)rel * (unsigned)(NN * 128);
    const float* esr = es + (unsigned)rel * (unsigned)(NN * 8);

    int e = beg;
    for (; e + 1 < end; e += 2) {
        int s0 = __builtin_amdgcn_readfirstlane(esrc[e]);
        int s1 = __builtin_amdgcn_readfirstlane(esrc[e + 1]);
        float e0 = esr[(unsigned)s0 * 8u + (unsigned)h];
        float e1 = esr[(unsigned)s1 * 8u + (unsigned)h];
        ushort2 u0 = *(const ushort2*)(Xr + (unsigned)s0 * 128u + (unsigned)f);
        ushort2 u1 = *(const ushort2*)(Xr + (unsigned)s1 * 128u + (unsigned)f);
        float aa0 = e0 + edv, aa1 = e1 + edv;
        float w0 = __expf(fmaxf(aa0, 0.2f * aa0));
        float w1 = __expf(fmaxf(aa1, 0.2f * aa1));
        a0 += w0 * us2f(u0.x) + w1 * us2f(u1.x);
        a1 += w0 * us2f(u0.y) + w1 * us2f(u1.y);
        den += w0 + w1;
    }
    if (e < end) {
        int s0 = __builtin_amdgcn_readfirstlane(esrc[e]);
        float e0 = esr[(unsigned)s0 * 8u + (unsigned)h];
        ushort2 u0 = *(const ushort2*)(Xr + (unsigned)s0 * 128u + (unsigned)f);
        float aa0 = e0 + edv;
        float w0 = __expf(fmaxf(aa0, 0.2f * aa0));
        a0 += w0 * us2f(u0.x);
        a1 += w0 * us2f(u0.y);
        den += w0;
    }

    float inv = den > 0.f ? 1.f / den : 0.f;
    float v0 = a0 * inv + bias_rel[(unsigned)rel * 128u + (unsigned)f];
    float v1 = a1 * inv + bias_rel[(unsigned)rel * 128u + (unsigned)f + 1u];
    v0 = 0.5f * v0 * (1.f + erff(v0 * 0.70710678118654752f));
    v1 = 0.5f * v1 * (1.f + erff(v1 * 0.70710678118654752f));
    bf16 g0 = __float2bfloat16(v0), g1 = __float2bfloat16(v1);
    ushort2 o;
    o.x = *(unsigned short*)&g0;
    o.y = *(unsigned short*)&g1;
    *(ushort2*)((unsigned short*)Gb4 + seg * 128u + (unsigned)f) = o;
}

// ---------------------------------------------------------------------------
// lang conv: per node 5-way softmax over {S, h0..h3}; S lives in `out`.
// ---------------------------------------------------------------------------
__global__ __launch_bounds__(256) void lang_kernel(
    const float* __restrict__ S, const bf16* __restrict__ Hb,
    const int* __restrict__ offsets,
    const float* __restrict__ att_src_lang, const float* __restrict__ att_dst_lang,
    const float* __restrict__ bias_lang, float* __restrict__ out)
{
    int n = blockIdx.x * 2 + (threadIdx.x >> 7);
    if (n >= NN) return;
    int d = threadIdx.x & 127;
    int h = d >> 4, dd = d & 15;

    float ent[5];
    ent[0] = S[(unsigned)n * 128u + (unsigned)d];
    #pragma unroll
    for (int r = 0; r < 4; ++r)
        ent[r + 1] = b2f(Hb[(unsigned)(r * NN + n) * 128u + (unsigned)d]);

    float asl = att_src_lang[h * 16 + dd];
    float adl = att_dst_lang[h * 16 + dd];

    float ls[5];
    #pragma unroll
    for (int k = 0; k < 5; ++k) ls[k] = ent[k] * asl;
    float ld = ent[0] * adl;

    #pragma unroll
    for (int off = 1; off < 16; off <<= 1) {
        #pragma unroll
        for (int k = 0; k < 5; ++k) ls[k] += __shfl_xor(ls[k], off);
        ld += __shfl_xor(ld, off);
    }

    bool valid[5];
    valid[0] = true;
    #pragma unroll
    for (int r = 0; r < 4; ++r) {
        int seg = r * NN + n;
        valid[r + 1] = offsets[seg + 1] > offsets[seg];
    }

    float logit[5], m = -1e30f;
    #pragma unroll
    for (int k = 0; k < 5; ++k) {
        float a = ls[k] + ld;
        float l = fmaxf(a, 0.2f * a);
        logit[k] = l;
        if (valid[k] && l > m) m = l;
    }
    float sum = 0.f, e[5];
    #pragma unroll
    for (int k = 0; k < 5; ++k) {
        e[k] = valid[k] ? __expf(logit[k] - m) : 0.f;
        sum += e[k];
    }
    float o = 0.f;
    #pragma unroll
    for (int k = 0; k < 5; ++k) o += e[k] * ent[k];
    o = o / sum + bias_lang[d];
    out[(unsigned)n * 128u + (unsigned)d] = o;
}

// ---------------------------------------------------------------------------
extern "C" void kernel_launch(void* const* d_in, const int* in_sizes, int n_in,
                              void* d_out, int out_size, void* d_ws, size_t ws_size,
                              hipStream_t stream) {
    const float* node_inp     = (const float*)d_in[0];
    const int*   edge_index   = (const int*)d_in[1];
    const int*   edge_type    = (const int*)d_in[2];
    const float* W_rel        = (const float*)d_in[3];
    const float* att_src_rel  = (const float*)d_in[4];
    const float* att_dst_rel  = (const float*)d_in[5];
    const float* bias_rel     = (const float*)d_in[6];
    const float* W_self       = (const float*)d_in[7];
    const float* W_cross      = (const float*)d_in[8];
    const float* att_src_lang = (const float*)d_in[9];
    const float* att_dst_lang = (const float*)d_in[10];
    const float* bias_lang    = (const float*)d_in[11];
    (void)in_sizes; (void)n_in;

    // workspace layout (bytes) — total ~120.3 MB (<121.6 MB proven)
    const size_t SZ_XB   = (size_t)NREL * NN * 128 * 2;   // 51,200,000 (bf16)
    const size_t SZ_ES   = (size_t)NREL * NN * 8 * 4;     //  6,400,000
    const size_t SZ_GB4  = (size_t)NREL * NN * 128 * 2;   // 51,200,000 (bf16)
    const size_t SZ_WT   = 768 * 128 * 2;                 //    196,608
    const size_t SZ_WCT  = 128 * 128 * 2;                 //     32,768
    const size_t SZ_ESRC = (size_t)NE * 4;                //  3,200,000
    const size_t SZ_OFF  = ((size_t)NSEG + 4) * 4;        //    800,016
    const size_t SZ_CNT  = (size_t)NSEG * 4;              //    800,000 (counts/cursor)
    const size_t SZ_PART = 4096;
    const size_t TOTAL = SZ_XB + 2 * SZ_ES + SZ_GB4 + SZ_WT + SZ_WCT +
                         SZ_ESRC + SZ_OFF + SZ_CNT + SZ_PART;

    if (ws_size < TOTAL) {
        fill_kernel<<<(out_size + 255) / 256, 256, 0, stream>>>((float*)d_out, out_size);
        return;
    }

    char* ws = (char*)d_ws;
    size_t o = 0;
    bf16*  Xb      = (bf16*)(ws + o);  o += SZ_XB;
    float* es      = (float*)(ws + o); o += SZ_ES;
    float* ed      = (float*)(ws + o); o += SZ_ES;
    bf16*  Gb4     = (bf16*)(ws + o);  o += SZ_GB4;
    bf16*  Wt      = (bf16*)(ws + o);  o += SZ_WT;
    bf16*  Wct     = (bf16*)(ws + o);  o += SZ_WCT;
    int*   esrc    = (int*)(ws + o);   o += SZ_ESRC;
    int*   offsets = (int*)(ws + o);   o += SZ_OFF;
    int*   counts  = (int*)(ws + o);   o += SZ_CNT;   // reused as cursor
    int*   partials= (int*)(ws + o);
    float* S       = (float*)d_out;  // S scratch in d_out; lang_kernel overwrites

    hipMemsetAsync(counts, 0, SZ_CNT, stream);

    conv_w_kernel<<<(768 * 128 + 128 * 128 + 255) / 256, 256, 0, stream>>>(
        W_rel, W_self, W_cross, att_src_rel, att_dst_rel, Wt, Wct);

    // fused GEMM: Xb (4 relations), S, es, ed in one pass
    dim3 g1((NN + 127) / 128, 6);
    gemm_mfma<0><<<g1, 256, 0, stream>>>(node_inp, Wt, Xb, S, es, ed, NN);

    // counting sort by (rel,dst)
    hist_kernel<<<(NE + 255) / 256, 256, 0, stream>>>(edge_index, edge_type, counts);
    scan1_kernel<<<NPART, 256, 0, stream>>>(counts, offsets, partials);
    scan2_kernel<<<1, 1024, 0, stream>>>(partials, offsets);
    scan3_kernel<<<NPART, 256, 0, stream>>>(offsets, partials, counts);
    scatter_kernel<<<(NE + 255) / 256, 256, 0, stream>>>(edge_index, edge_type, counts, esrc);

    // batched aggregation over all relations
    dim3 ga((NN + 3) / 4, NREL);
    agg_kernel<<<ga, 256, 0, stream>>>(esrc, offsets, Xb, es, ed, bias_rel, Gb4);

    // batched cross-GEMM: [4*NN,128] @ Wct -> Hb (overwrites Xb)
    dim3 g2((NREL * NN + 127) / 128, 1);
    gemm_mfma<1><<<g2, 256, 0, stream>>>(Gb4, Wct, Xb, nullptr, nullptr, nullptr, NREL * NN);

    lang_kernel<<<NN / 2, 256, 0, stream>>>(S, Xb, offsets, att_src_lang, att_dst_lang,
                                            bias_lang, (float*)d_out);
}

// Round 9
// 354.460 us; speedup vs baseline: 4.0960x; 1.0116x over previous
//
#include <hip/hip_runtime.h>
#include <hip/hip_bf16.h>
#include <math.h>

#define NN 50000
#define NE 800000
#define NREL 4
#define NHEAD 8
#define NSEG (NREL * NN)            // 200000 (rel,dst) segments
#define NPART ((NSEG + 255) / 256)  // 782 scan partials

typedef __hip_bfloat16 bf16;
typedef short short8 __attribute__((ext_vector_type(8)));
typedef float floatx4 __attribute__((ext_vector_type(4)));

#define LOG2E 1.4426950408889634f

__device__ __forceinline__ float b2f(bf16 v) { return __bfloat162float(v); }
__device__ __forceinline__ float us2f(unsigned short u) {
    return __uint_as_float(((unsigned)u) << 16);
}

// Exact-enough GELU: erf via Abramowitz-Stegun 7.1.26 (|err| <= 1.5e-7),
// exp via v_exp_f32. ~15 VALU ops vs ~35 for libm erff.
__device__ __forceinline__ float gelu_f(float v) {
    float z = v * 0.70710678118654752f;
    float az = fabsf(z);
    float t = __builtin_amdgcn_rcpf(__builtin_fmaf(0.3275911f, az, 1.f));
    float p = t * (0.254829592f +
              t * (-0.284496736f +
              t * (1.421413741f +
              t * (-1.453152027f +
              t * 1.061405429f))));
    float ex = __builtin_amdgcn_exp2f(az * az * -LOG2E);
    float er = copysignf(1.f - p * ex, z);
    return 0.5f * v * (1.f + er);
}

// ---------------------------------------------------------------------------
// Diagnostic: fill out with 1000.0 when ws_size is insufficient
// ---------------------------------------------------------------------------
__global__ void fill_kernel(float* __restrict__ out, int n) {
    int t = blockIdx.x * blockDim.x + threadIdx.x;
    if (t < n) out[t] = 1000.0f;
}

// ---------------------------------------------------------------------------
// Pack weights transposed to [outcol][k] bf16, AND zero the sort counters.
// Wt[768][128]: rows 0..511 W_rel, 512..639 W_self,
//               640..671 es-vectors (log2e * W_r @ a_src), 672..703 ed-vectors
//               (log2e-scaled), 704..767 zero padding.
// Wct[128][128]: W_cross transposed.
// Grid covers max(114688, NSEG) threads.
// ---------------------------------------------------------------------------
__global__ void prep_kernel(const float* __restrict__ W_rel,
                            const float* __restrict__ W_self,
                            const float* __restrict__ W_cross,
                            const float* __restrict__ a_src,
                            const float* __restrict__ a_dst,
                            bf16* __restrict__ Wt, bf16* __restrict__ Wct,
                            int* __restrict__ counts) {
    int t = blockIdx.x * blockDim.x + threadIdx.x;
    if (t < NSEG) counts[t] = 0;
    if (t < 768 * 128) {
        int row = t >> 7, k = t & 127;
        float v;
        if (row < 512) {
            int r = row >> 7, c = row & 127;
            v = W_rel[(r * 128 + k) * 128 + c];
        } else if (row < 640) {
            v = W_self[k * 128 + (row - 512)];
        } else if (row < 704) {
            int q = row - 640;
            bool is_src = q < 32;
            int qq = is_src ? q : q - 32;
            int r = qq >> 3, h = qq & 7;
            const float* av = (is_src ? a_src : a_dst) + (r * 8 + h) * 16;
            const float* wr = W_rel + (size_t)(r * 128 + k) * 128 + h * 16;
            float s = 0.f;
            #pragma unroll
            for (int dd = 0; dd < 16; ++dd) s += wr[dd] * av[dd];
            v = s * LOG2E;   // prescale so agg uses exp2 directly
        } else {
            v = 0.f;
        }
        Wt[t] = __float2bfloat16(v);
    } else if (t < 768 * 128 + 128 * 128) {
        int u = t - 768 * 128;
        int n = u >> 7, k = u & 127;
        Wct[u] = __float2bfloat16(W_cross[k * 128 + n]);
    }
}

// ---------------------------------------------------------------------------
// MFMA GEMM. A fp32 [M,128] (MODE 0, converted during staging) or bf16 (MODE 1).
// Bt[Ncols,128] bf16 (B^T, k-contig).
// MODE 0 (grid.y=6): y<4 -> Xb[y,:,:] bf16 (coalesced via LDS transpose);
//                    y=4 -> S f32; y=5 -> es/ed f32 (scattered, small).
// MODE 1 (grid.y=1): outb[M,128] bf16.
// ---------------------------------------------------------------------------
template<int MODE>
__global__ __launch_bounds__(256) void gemm_mfma(
    const void* __restrict__ Ain,
    const bf16* __restrict__ Bt,
    bf16* __restrict__ outb,
    float* __restrict__ outf,
    float* __restrict__ es,
    float* __restrict__ ed,
    int M)
{
    __shared__ __align__(16) char smem[20480];
    short (*As)[40] = (short (*)[40])smem;
    short (*Bs)[40] = (short (*)[40])(smem + 10240);

    const int tid  = threadIdx.x;
    const int wave = tid >> 6, lane = tid & 63;
    const int quad = lane >> 4, l16 = lane & 15;
    const int wq = wave >> 1, wc = wave & 1;
    const int row0 = blockIdx.x * 128;
    const int col0 = blockIdx.y * 128;

    floatx4 acc[4][4];
    #pragma unroll
    for (int i = 0; i < 4; ++i)
        #pragma unroll
        for (int j = 0; j < 4; ++j) acc[i][j] = (floatx4){0.f, 0.f, 0.f, 0.f};

    for (int k0 = 0; k0 < 128; k0 += 32) {
        #pragma unroll
        for (int i = 0; i < 2; ++i) {
            int c = tid * 2 + i;                  // 512 chunks of 8 elems
            int r = c >> 2, off = (c & 3) * 8;
            int gr = row0 + r;
            short8 v = {0, 0, 0, 0, 0, 0, 0, 0};
            if (MODE == 0) {
                if (gr < M) {
                    const float* ap = (const float*)Ain + (((size_t)gr) << 7) + k0 + off;
                    float4 f0 = *(const float4*)ap;
                    float4 f1 = *(const float4*)(ap + 4);
                    bf16 b0 = __float2bfloat16(f0.x), b1 = __float2bfloat16(f0.y);
                    bf16 b2 = __float2bfloat16(f0.z), b3 = __float2bfloat16(f0.w);
                    bf16 b4 = __float2bfloat16(f1.x), b5 = __float2bfloat16(f1.y);
                    bf16 b6 = __float2bfloat16(f1.z), b7 = __float2bfloat16(f1.w);
                    v = (short8){*(short*)&b0, *(short*)&b1, *(short*)&b2, *(short*)&b3,
                                 *(short*)&b4, *(short*)&b5, *(short*)&b6, *(short*)&b7};
                }
            } else {
                if (gr < M)
                    v = *(const short8*)((const bf16*)Ain + (((size_t)gr) << 7) + k0 + off);
            }
            *(short8*)&As[r][off] = v;
            short8 w = *(const short8*)(Bt + (((size_t)(col0 + r)) << 7) + k0 + off);
            *(short8*)&Bs[r][off] = w;
        }
        __syncthreads();

        short8 av[4], bv[4];
        #pragma unroll
        for (int mt = 0; mt < 4; ++mt)
            av[mt] = *(const short8*)&As[wq * 64 + mt * 16 + l16][quad * 8];
        #pragma unroll
        for (int nt = 0; nt < 4; ++nt)
            bv[nt] = *(const short8*)&Bs[wc * 64 + nt * 16 + l16][quad * 8];
        #pragma unroll
        for (int mt = 0; mt < 4; ++mt)
            #pragma unroll
            for (int nt = 0; nt < 4; ++nt)
                acc[mt][nt] = __builtin_amdgcn_mfma_f32_16x16x32_bf16(
                    av[mt], bv[nt], acc[mt][nt], 0, 0, 0);
        __syncthreads();
    }

    // ---------------- epilogue ----------------
    if (MODE == 0 && blockIdx.y == 5) {
        // es/ed columns: gc = 640 + wc*64 + nt*16 + l16; wc==1 -> padding, skip
        if (wc == 0) {
            #pragma unroll
            for (int mt = 0; mt < 4; ++mt) {
                #pragma unroll
                for (int reg = 0; reg < 4; ++reg) {
                    int gr = row0 + wq * 64 + mt * 16 + quad * 4 + reg;
                    if (gr >= M) continue;
                    #pragma unroll
                    for (int nt = 0; nt < 4; ++nt) {
                        int q = nt * 16 + l16;          // 0..63
                        float v = acc[mt][nt][reg];
                        if (q < 32)
                            es[(size_t)((q >> 3) * NN + gr) * 8 + (q & 7)] = v;
                        else
                            ed[(size_t)(((q - 32) >> 3) * NN + gr) * 8 + ((q - 32) & 7)] = v;
                    }
                }
            }
        }
        return;
    }

    // LDS-transpose path: wave-private [16][68] f32 region
    float* ct = (float*)(smem + wave * 5120);
    const int rr2 = lane >> 2;
    const int cc0 = (lane & 3) * 16;

    for (int mt = 0; mt < 4; ++mt) {
        #pragma unroll
        for (int nt = 0; nt < 4; ++nt)
            #pragma unroll
            for (int reg = 0; reg < 4; ++reg)
                ct[(quad * 4 + reg) * 68 + nt * 16 + l16] = acc[mt][nt][reg];
        __syncthreads();

        int gr2 = row0 + wq * 64 + mt * 16 + rr2;
        if (gr2 < M) {
            float4 f0 = *(const float4*)&ct[rr2 * 68 + cc0];
            float4 f1 = *(const float4*)&ct[rr2 * 68 + cc0 + 4];
            float4 f2 = *(const float4*)&ct[rr2 * 68 + cc0 + 8];
            float4 f3 = *(const float4*)&ct[rr2 * 68 + cc0 + 12];
            int cb = wc * 64 + cc0;
            if (MODE == 0 && blockIdx.y == 4) {
                float* dst = outf + (((size_t)gr2) << 7) + cb;
                ((float4*)dst)[0] = f0;
                ((float4*)dst)[1] = f1;
                ((float4*)dst)[2] = f2;
                ((float4*)dst)[3] = f3;
            } else {
                float tmp[16] = {f0.x, f0.y, f0.z, f0.w, f1.x, f1.y, f1.z, f1.w,
                                 f2.x, f2.y, f2.z, f2.w, f3.x, f3.y, f3.z, f3.w};
                short8 o0, o1;
                #pragma unroll
                for (int j = 0; j < 8; ++j) {
                    bf16 b = __float2bfloat16(tmp[j]);
                    o0[j] = *(short*)&b;
                }
                #pragma unroll
                for (int j = 0; j < 8; ++j) {
                    bf16 b = __float2bfloat16(tmp[8 + j]);
                    o1[j] = *(short*)&b;
                }
                bf16* dst;
                if (MODE == 0)
                    dst = outb + ((size_t)(blockIdx.y * NN + gr2) << 7) + cb;
                else
                    dst = outb + (((size_t)gr2) << 7) + cb;
                *(short8*)dst = o0;
                *(short8*)(dst + 8) = o1;
            }
        }
        __syncthreads();
    }
}

// ---------------------------------------------------------------------------
// Counting sort of edges by seg = rel*NN + dst  (histogram / scan / scatter)
// ---------------------------------------------------------------------------
__global__ void hist_kernel(const int* __restrict__ ei, const int* __restrict__ et,
                            int* __restrict__ counts) {
    int e = blockIdx.x * 256 + threadIdx.x;
    if (e >= NE) return;
    int seg = et[e] * NN + ei[NE + e];
    atomicAdd(&counts[seg], 1);
}

__global__ __launch_bounds__(256) void scan1_kernel(const int* __restrict__ counts,
                                                    int* __restrict__ offsets,
                                                    int* __restrict__ partials) {
    __shared__ int sm[256];
    int b = blockIdx.x, t = threadIdx.x, i = b * 256 + t;
    int v = (i < NSEG) ? counts[i] : 0;
    sm[t] = v;
    __syncthreads();
    #pragma unroll
    for (int off = 1; off < 256; off <<= 1) {
        int x = sm[t];
        int y = (t >= off) ? sm[t - off] : 0;
        __syncthreads();
        sm[t] = x + y;
        __syncthreads();
    }
    if (i < NSEG) offsets[i] = sm[t] - v;   // chunk-local exclusive
    if (t == 255) partials[b] = sm[255];
}

__global__ __launch_bounds__(1024) void scan2_kernel(int* __restrict__ partials,
                                                     int* __restrict__ offsets) {
    __shared__ int sm[1024];
    int t = threadIdx.x;
    int v = (t < NPART) ? partials[t] : 0;
    sm[t] = v;
    __syncthreads();
    #pragma unroll
    for (int off = 1; off < 1024; off <<= 1) {
        int x = sm[t];
        int y = (t >= off) ? sm[t - off] : 0;
        __syncthreads();
        sm[t] = x + y;
        __syncthreads();
    }
    if (t < NPART) partials[t] = sm[t] - v;  // exclusive partial prefix
    if (t == 0) offsets[NSEG] = NE;
}

__global__ __launch_bounds__(256) void scan3_kernel(int* __restrict__ offsets,
                                                    const int* __restrict__ partials,
                                                    int* __restrict__ cursor) {
    int b = blockIdx.x, i = b * 256 + threadIdx.x;
    if (i >= NSEG) return;
    int v = offsets[i] + partials[b];
    offsets[i] = v;
    cursor[i] = v;
}

__global__ void scatter_kernel(const int* __restrict__ ei, const int* __restrict__ et,
                               int* __restrict__ cursor, int* __restrict__ esrc) {
    int e = blockIdx.x * 256 + threadIdx.x;
    if (e >= NE) return;
    int seg = et[e] * NN + ei[NE + e];
    int pos = atomicAdd(&cursor[seg], 1);
    esrc[pos] = ei[e];
}

// ---------------------------------------------------------------------------
// Batched aggregation: grid.y = rel. 64 lanes per dst node walk its CSR slice.
// Scalarized + unroll-4 loop; exp2 weights (logits prescaled by log2e in Wt);
// A-S exact GELU. lane l covers features {2l, 2l+1}; head h = l>>3.
// ---------------------------------------------------------------------------
__global__ __launch_bounds__(256) void agg_kernel(
    const int* __restrict__ esrc, const int* __restrict__ offsets,
    const bf16* __restrict__ Xb, const float* __restrict__ es,
    const float* __restrict__ ed, const float* __restrict__ bias_rel,
    bf16* __restrict__ Gb4)
{
    const int rel = blockIdx.y;
    const int n = blockIdx.x * 4 + (threadIdx.x >> 6);
    if (n >= NN) return;
    const int l = threadIdx.x & 63;
    const int h = l >> 3;
    const int f = l * 2;
    const unsigned seg = (unsigned)(rel * NN + n);
    int beg = __builtin_amdgcn_readfirstlane(offsets[seg]);
    int end = __builtin_amdgcn_readfirstlane(offsets[seg + 1]);
    const float edv = ed[seg * 8u + (unsigned)h];
    float a0 = 0.f, a1 = 0.f, den = 0.f;
    const unsigned short* Xr = (const unsigned short*)Xb + (unsigned)rel * (unsigned)(NN * 128);
    const float* esr = es + (unsigned)rel * (unsigned)(NN * 8);

    int e = beg;
    for (; e + 3 < end; e += 4) {
        int s0 = __builtin_amdgcn_readfirstlane(esrc[e]);
        int s1 = __builtin_amdgcn_readfirstlane(esrc[e + 1]);
        int s2 = __builtin_amdgcn_readfirstlane(esrc[e + 2]);
        int s3 = __builtin_amdgcn_readfirstlane(esrc[e + 3]);
        float e0 = esr[(unsigned)s0 * 8u + (unsigned)h];
        float e1 = esr[(unsigned)s1 * 8u + (unsigned)h];
        float e2 = esr[(unsigned)s2 * 8u + (unsigned)h];
        float e3 = esr[(unsigned)s3 * 8u + (unsigned)h];
        ushort2 u0 = *(const ushort2*)(Xr + (unsigned)s0 * 128u + (unsigned)f);
        ushort2 u1 = *(const ushort2*)(Xr + (unsigned)s1 * 128u + (unsigned)f);
        ushort2 u2 = *(const ushort2*)(Xr + (unsigned)s2 * 128u + (unsigned)f);
        ushort2 u3 = *(const ushort2*)(Xr + (unsigned)s3 * 128u + (unsigned)f);
        float aa0 = e0 + edv, aa1 = e1 + edv, aa2 = e2 + edv, aa3 = e3 + edv;
        float w0 = __builtin_amdgcn_exp2f(fmaxf(aa0, 0.2f * aa0));
        float w1 = __builtin_amdgcn_exp2f(fmaxf(aa1, 0.2f * aa1));
        float w2 = __builtin_amdgcn_exp2f(fmaxf(aa2, 0.2f * aa2));
        float w3 = __builtin_amdgcn_exp2f(fmaxf(aa3, 0.2f * aa3));
        a0 += w0 * us2f(u0.x) + w1 * us2f(u1.x) + w2 * us2f(u2.x) + w3 * us2f(u3.x);
        a1 += w0 * us2f(u0.y) + w1 * us2f(u1.y) + w2 * us2f(u2.y) + w3 * us2f(u3.y);
        den += (w0 + w1) + (w2 + w3);
    }
    for (; e < end; ++e) {
        int s0 = __builtin_amdgcn_readfirstlane(esrc[e]);
        float e0 = esr[(unsigned)s0 * 8u + (unsigned)h];
        ushort2 u0 = *(const ushort2*)(Xr + (unsigned)s0 * 128u + (unsigned)f);
        float aa0 = e0 + edv;
        float w0 = __builtin_amdgcn_exp2f(fmaxf(aa0, 0.2f * aa0));
        a0 += w0 * us2f(u0.x);
        a1 += w0 * us2f(u0.y);
        den += w0;
    }

    float inv = den > 0.f ? __builtin_amdgcn_rcpf(den) : 0.f;
    float2 bv = *(const float2*)(bias_rel + (unsigned)rel * 128u + (unsigned)f);
    float v0 = __builtin_fmaf(a0, inv, bv.x);
    float v1 = __builtin_fmaf(a1, inv, bv.y);
    v0 = gelu_f(v0);
    v1 = gelu_f(v1);
    bf16 g0 = __float2bfloat16(v0), g1 = __float2bfloat16(v1);
    ushort2 o;
    o.x = *(unsigned short*)&g0;
    o.y = *(unsigned short*)&g1;
    *(ushort2*)((unsigned short*)Gb4 + seg * 128u + (unsigned)f) = o;
}

// ---------------------------------------------------------------------------
// lang conv: per node 5-way softmax over {S, h0..h3}; S lives in `out`.
// ---------------------------------------------------------------------------
__global__ __launch_bounds__(256) void lang_kernel(
    const float* __restrict__ S, const bf16* __restrict__ Hb,
    const int* __restrict__ offsets,
    const float* __restrict__ att_src_lang, const float* __restrict__ att_dst_lang,
    const float* __restrict__ bias_lang, float* __restrict__ out)
{
    int n = blockIdx.x * 2 + (threadIdx.x >> 7);
    if (n >= NN) return;
    int d = threadIdx.x & 127;
    int h = d >> 4, dd = d & 15;

    float ent[5];
    ent[0] = S[(unsigned)n * 128u + (unsigned)d];
    #pragma unroll
    for (int r = 0; r < 4; ++r)
        ent[r + 1] = b2f(Hb[(unsigned)(r * NN + n) * 128u + (unsigned)d]);

    float asl = att_src_lang[h * 16 + dd];
    float adl = att_dst_lang[h * 16 + dd];

    float ls[5];
    #pragma unroll
    for (int k = 0; k < 5; ++k) ls[k] = ent[k] * asl;
    float ld = ent[0] * adl;

    #pragma unroll
    for (int off = 1; off < 16; off <<= 1) {
        #pragma unroll
        for (int k = 0; k < 5; ++k) ls[k] += __shfl_xor(ls[k], off);
        ld += __shfl_xor(ld, off);
    }

    bool valid[5];
    valid[0] = true;
    #pragma unroll
    for (int r = 0; r < 4; ++r) {
        int seg = r * NN + n;
        valid[r + 1] = offsets[seg + 1] > offsets[seg];
    }

    float logit[5], m = -1e30f;
    #pragma unroll
    for (int k = 0; k < 5; ++k) {
        float a = ls[k] + ld;
        float l = fmaxf(a, 0.2f * a);
        logit[k] = l;
        if (valid[k] && l > m) m = l;
    }
    float sum = 0.f, e[5];
    #pragma unroll
    for (int k = 0; k < 5; ++k) {
        e[k] = valid[k] ? __expf(logit[k] - m) : 0.f;
        sum += e[k];
    }
    float o = 0.f;
    #pragma unroll
    for (int k = 0; k < 5; ++k) o += e[k] * ent[k];
    o = o / sum + bias_lang[d];
    out[(unsigned)n * 128u + (unsigned)d] = o;
}

// ---------------------------------------------------------------------------
extern "C" void kernel_launch(void* const* d_in, const int* in_sizes, int n_in,
                              void* d_out, int out_size, void* d_ws, size_t ws_size,
                              hipStream_t stream) {
    const float* node_inp     = (const float*)d_in[0];
    const int*   edge_index   = (const int*)d_in[1];
    const int*   edge_type    = (const int*)d_in[2];
    const float* W_rel        = (const float*)d_in[3];
    const float* att_src_rel  = (const float*)d_in[4];
    const float* att_dst_rel  = (const float*)d_in[5];
    const float* bias_rel     = (const float*)d_in[6];
    const float* W_self       = (const float*)d_in[7];
    const float* W_cross      = (const float*)d_in[8];
    const float* att_src_lang = (const float*)d_in[9];
    const float* att_dst_lang = (const float*)d_in[10];
    const float* bias_lang    = (const float*)d_in[11];
    (void)in_sizes; (void)n_in;

    // workspace layout (bytes) — total ~120.3 MB (<121.6 MB proven)
    const size_t SZ_XB   = (size_t)NREL * NN * 128 * 2;   // 51,200,000 (bf16)
    const size_t SZ_ES   = (size_t)NREL * NN * 8 * 4;     //  6,400,000
    const size_t SZ_GB4  = (size_t)NREL * NN * 128 * 2;   // 51,200,000 (bf16)
    const size_t SZ_WT   = 768 * 128 * 2;                 //    196,608
    const size_t SZ_WCT  = 128 * 128 * 2;                 //     32,768
    const size_t SZ_ESRC = (size_t)NE * 4;                //  3,200,000
    const size_t SZ_OFF  = ((size_t)NSEG + 4) * 4;        //    800,016
    const size_t SZ_CNT  = (size_t)NSEG * 4;              //    800,000 (counts/cursor)
    const size_t SZ_PART = 4096;
    const size_t TOTAL = SZ_XB + 2 * SZ_ES + SZ_GB4 + SZ_WT + SZ_WCT +
                         SZ_ESRC + SZ_OFF + SZ_CNT + SZ_PART;

    if (ws_size < TOTAL) {
        fill_kernel<<<(out_size + 255) / 256, 256, 0, stream>>>((float*)d_out, out_size);
        return;
    }

    char* ws = (char*)d_ws;
    size_t o = 0;
    bf16*  Xb      = (bf16*)(ws + o);  o += SZ_XB;
    float* es      = (float*)(ws + o); o += SZ_ES;
    float* ed      = (float*)(ws + o); o += SZ_ES;
    bf16*  Gb4     = (bf16*)(ws + o);  o += SZ_GB4;
    bf16*  Wt      = (bf16*)(ws + o);  o += SZ_WT;
    bf16*  Wct     = (bf16*)(ws + o);  o += SZ_WCT;
    int*   esrc    = (int*)(ws + o);   o += SZ_ESRC;
    int*   offsets = (int*)(ws + o);   o += SZ_OFF;
    int*   counts  = (int*)(ws + o);   o += SZ_CNT;   // reused as cursor
    int*   partials= (int*)(ws + o);
    float* S       = (float*)d_out;  // S scratch in d_out; lang_kernel overwrites

    // pack weights (with log2e-prescaled att columns) + zero counts
    prep_kernel<<<(NSEG + 255) / 256, 256, 0, stream>>>(
        W_rel, W_self, W_cross, att_src_rel, att_dst_rel, Wt, Wct, counts);

    // fused GEMM: Xb (4 relations), S, es, ed in one pass
    dim3 g1((NN + 127) / 128, 6);
    gemm_mfma<0><<<g1, 256, 0, stream>>>(node_inp, Wt, Xb, S, es, ed, NN);

    // counting sort by (rel,dst)
    hist_kernel<<<(NE + 255) / 256, 256, 0, stream>>>(edge_index, edge_type, counts);
    scan1_kernel<<<NPART, 256, 0, stream>>>(counts, offsets, partials);
    scan2_kernel<<<1, 1024, 0, stream>>>(partials, offsets);
    scan3_kernel<<<NPART, 256, 0, stream>>>(offsets, partials, counts);
    scatter_kernel<<<(NE + 255) / 256, 256, 0, stream>>>(edge_index, edge_type, counts, esrc);

    // batched aggregation over all relations
    dim3 ga((NN + 3) / 4, NREL);
    agg_kernel<<<ga, 256, 0, stream>>>(esrc, offsets, Xb, es, ed, bias_rel, Gb4);

    // batched cross-GEMM: [4*NN,128] @ Wct -> Hb (overwrites Xb)
    dim3 g2((NREL * NN + 127) / 128, 1);
    gemm_mfma<1><<<g2, 256, 0, stream>>>(Gb4, Wct, Xb, nullptr, nullptr, nullptr, NREL * NN);

    lang_kernel<<<NN / 2, 256, 0, stream>>>(S, Xb, offsets, att_src_lang, att_dst_lang,
                                            bias_lang, (float*)d_out);
}

// Round 10
// 349.728 us; speedup vs baseline: 4.1515x; 1.0135x over previous
//
#include <hip/hip_runtime.h>
#include <hip/hip_bf16.h>
#include <math.h>

#define NN 50000
#define NE 800000
#define NREL 4
#define NHEAD 8
#define NSEG (NREL * NN)            // 200000 (rel,dst) segments
#define NPART ((NSEG + 255) / 256)  // 782 scan partials

typedef __hip_bfloat16 bf16;
typedef short short8 __attribute__((ext_vector_type(8)));
typedef float floatx4 __attribute__((ext_vector_type(4)));

#define LOG2E 1.4426950408889634f

__device__ __forceinline__ float b2f(bf16 v) { return __bfloat162float(v); }
__device__ __forceinline__ float us2f(unsigned short u) {
    return __uint_as_float(((unsigned)u) << 16);
}

// Exact-enough GELU: erf via Abramowitz-Stegun 7.1.26 (|err| <= 1.5e-7).
__device__ __forceinline__ float gelu_f(float v) {
    float z = v * 0.70710678118654752f;
    float az = fabsf(z);
    float t = __builtin_amdgcn_rcpf(__builtin_fmaf(0.3275911f, az, 1.f));
    float p = t * (0.254829592f +
              t * (-0.284496736f +
              t * (1.421413741f +
              t * (-1.453152027f +
              t * 1.061405429f))));
    float ex = __builtin_amdgcn_exp2f(az * az * -LOG2E);
    float er = copysignf(1.f - p * ex, z);
    return 0.5f * v * (1.f + er);
}

// ---------------------------------------------------------------------------
// Diagnostic: fill out with 1000.0 when ws_size is insufficient
// ---------------------------------------------------------------------------
__global__ void fill_kernel(float* __restrict__ out, int n) {
    int t = blockIdx.x * blockDim.x + threadIdx.x;
    if (t < n) out[t] = 1000.0f;
}

// ---------------------------------------------------------------------------
// Pack weights transposed to [outcol][k] bf16, AND zero the sort counters.
// Wt[768][128]: rows 0..511 W_rel, 512..639 W_self,
//               640..671 es-vectors (log2e * W_r @ a_src), 672..703 ed-vectors
//               (log2e-scaled), 704..767 zero padding.
// Wct[128][128]: W_cross transposed.
// ---------------------------------------------------------------------------
__global__ void prep_kernel(const float* __restrict__ W_rel,
                            const float* __restrict__ W_self,
                            const float* __restrict__ W_cross,
                            const float* __restrict__ a_src,
                            const float* __restrict__ a_dst,
                            bf16* __restrict__ Wt, bf16* __restrict__ Wct,
                            int* __restrict__ counts) {
    int t = blockIdx.x * blockDim.x + threadIdx.x;
    if (t < NSEG) counts[t] = 0;
    if (t < 768 * 128) {
        int row = t >> 7, k = t & 127;
        float v;
        if (row < 512) {
            int r = row >> 7, c = row & 127;
            v = W_rel[(r * 128 + k) * 128 + c];
        } else if (row < 640) {
            v = W_self[k * 128 + (row - 512)];
        } else if (row < 704) {
            int q = row - 640;
            bool is_src = q < 32;
            int qq = is_src ? q : q - 32;
            int r = qq >> 3, h = qq & 7;
            const float* av = (is_src ? a_src : a_dst) + (r * 8 + h) * 16;
            const float* wr = W_rel + (size_t)(r * 128 + k) * 128 + h * 16;
            float s = 0.f;
            #pragma unroll
            for (int dd = 0; dd < 16; ++dd) s += wr[dd] * av[dd];
            v = s * LOG2E;   // prescale so agg uses exp2 directly
        } else {
            v = 0.f;
        }
        Wt[t] = __float2bfloat16(v);
    } else if (t < 768 * 128 + 128 * 128) {
        int u = t - 768 * 128;
        int n = u >> 7, k = u & 127;
        Wct[u] = __float2bfloat16(W_cross[k * 128 + n]);
    }
}

// ---------------------------------------------------------------------------
// MFMA GEMM, MODE 0 only (verified R7/R8): A fp32 [M,128] converted during
// staging; Bt[768,128] bf16. grid.y=6: y<4 -> Xb[y] bf16 (LDS-transposed,
// coalesced); y=4 -> S f32; y=5 -> es/ed f32 (scattered, small).
// ---------------------------------------------------------------------------
__global__ __launch_bounds__(256) void gemm_node(
    const float* __restrict__ Ain,
    const bf16* __restrict__ Bt,
    bf16* __restrict__ outb,
    float* __restrict__ outf,
    float* __restrict__ es,
    float* __restrict__ ed,
    int M)
{
    __shared__ __align__(16) char smem[20480];
    short (*As)[40] = (short (*)[40])smem;
    short (*Bs)[40] = (short (*)[40])(smem + 10240);

    const int tid  = threadIdx.x;
    const int wave = tid >> 6, lane = tid & 63;
    const int quad = lane >> 4, l16 = lane & 15;
    const int wq = wave >> 1, wc = wave & 1;
    const int row0 = blockIdx.x * 128;
    const int col0 = blockIdx.y * 128;

    floatx4 acc[4][4];
    #pragma unroll
    for (int i = 0; i < 4; ++i)
        #pragma unroll
        for (int j = 0; j < 4; ++j) acc[i][j] = (floatx4){0.f, 0.f, 0.f, 0.f};

    for (int k0 = 0; k0 < 128; k0 += 32) {
        #pragma unroll
        for (int i = 0; i < 2; ++i) {
            int c = tid * 2 + i;
            int r = c >> 2, off = (c & 3) * 8;
            int gr = row0 + r;
            short8 v = {0, 0, 0, 0, 0, 0, 0, 0};
            if (gr < M) {
                const float* ap = Ain + (((size_t)gr) << 7) + k0 + off;
                float4 f0 = *(const float4*)ap;
                float4 f1 = *(const float4*)(ap + 4);
                bf16 b0 = __float2bfloat16(f0.x), b1 = __float2bfloat16(f0.y);
                bf16 b2 = __float2bfloat16(f0.z), b3 = __float2bfloat16(f0.w);
                bf16 b4 = __float2bfloat16(f1.x), b5 = __float2bfloat16(f1.y);
                bf16 b6 = __float2bfloat16(f1.z), b7 = __float2bfloat16(f1.w);
                v = (short8){*(short*)&b0, *(short*)&b1, *(short*)&b2, *(short*)&b3,
                             *(short*)&b4, *(short*)&b5, *(short*)&b6, *(short*)&b7};
            }
            *(short8*)&As[r][off] = v;
            short8 w = *(const short8*)(Bt + (((size_t)(col0 + r)) << 7) + k0 + off);
            *(short8*)&Bs[r][off] = w;
        }
        __syncthreads();

        short8 av[4], bv[4];
        #pragma unroll
        for (int mt = 0; mt < 4; ++mt)
            av[mt] = *(const short8*)&As[wq * 64 + mt * 16 + l16][quad * 8];
        #pragma unroll
        for (int nt = 0; nt < 4; ++nt)
            bv[nt] = *(const short8*)&Bs[wc * 64 + nt * 16 + l16][quad * 8];
        #pragma unroll
        for (int mt = 0; mt < 4; ++mt)
            #pragma unroll
            for (int nt = 0; nt < 4; ++nt)
                acc[mt][nt] = __builtin_amdgcn_mfma_f32_16x16x32_bf16(
                    av[mt], bv[nt], acc[mt][nt], 0, 0, 0);
        __syncthreads();
    }

    if (blockIdx.y == 5) {
        if (wc == 0) {
            #pragma unroll
            for (int mt = 0; mt < 4; ++mt) {
                #pragma unroll
                for (int reg = 0; reg < 4; ++reg) {
                    int gr = row0 + wq * 64 + mt * 16 + quad * 4 + reg;
                    if (gr >= M) continue;
                    #pragma unroll
                    for (int nt = 0; nt < 4; ++nt) {
                        int q = nt * 16 + l16;
                        float v = acc[mt][nt][reg];
                        if (q < 32)
                            es[(size_t)((q >> 3) * NN + gr) * 8 + (q & 7)] = v;
                        else
                            ed[(size_t)(((q - 32) >> 3) * NN + gr) * 8 + ((q - 32) & 7)] = v;
                    }
                }
            }
        }
        return;
    }

    // LDS-transpose path: wave-private [16][68] f32 region
    float* ct = (float*)(smem + wave * 5120);
    const int rr2 = lane >> 2;
    const int cc0 = (lane & 3) * 16;

    for (int mt = 0; mt < 4; ++mt) {
        #pragma unroll
        for (int nt = 0; nt < 4; ++nt)
            #pragma unroll
            for (int reg = 0; reg < 4; ++reg)
                ct[(quad * 4 + reg) * 68 + nt * 16 + l16] = acc[mt][nt][reg];
        __syncthreads();

        int gr2 = row0 + wq * 64 + mt * 16 + rr2;
        if (gr2 < M) {
            float4 f0 = *(const float4*)&ct[rr2 * 68 + cc0];
            float4 f1 = *(const float4*)&ct[rr2 * 68 + cc0 + 4];
            float4 f2 = *(const float4*)&ct[rr2 * 68 + cc0 + 8];
            float4 f3 = *(const float4*)&ct[rr2 * 68 + cc0 + 12];
            int cb = wc * 64 + cc0;
            if (blockIdx.y == 4) {
                float* dst = outf + (((size_t)gr2) << 7) + cb;
                ((float4*)dst)[0] = f0;
                ((float4*)dst)[1] = f1;
                ((float4*)dst)[2] = f2;
                ((float4*)dst)[3] = f3;
            } else {
                float tmp[16] = {f0.x, f0.y, f0.z, f0.w, f1.x, f1.y, f1.z, f1.w,
                                 f2.x, f2.y, f2.z, f2.w, f3.x, f3.y, f3.z, f3.w};
                short8 o0, o1;
                #pragma unroll
                for (int j = 0; j < 8; ++j) {
                    bf16 b = __float2bfloat16(tmp[j]);
                    o0[j] = *(short*)&b;
                }
                #pragma unroll
                for (int j = 0; j < 8; ++j) {
                    bf16 b = __float2bfloat16(tmp[8 + j]);
                    o1[j] = *(short*)&b;
                }
                bf16* dst = outb + ((size_t)(blockIdx.y * NN + gr2) << 7) + cb;
                *(short8*)dst = o0;
                *(short8*)(dst + 8) = o1;
            }
        }
        __syncthreads();
    }
}

// ---------------------------------------------------------------------------
// Fused cross-GEMM + lang softmax.
// A = Gb4 node-major bf16 [NN*4,128] (row = n*4+rel), Bt = Wct.
// MFMA C-layout gives reg = rel, quad = node within each 16x16 tile; each
// head's 16 dims = the 16 l16 lanes -> per-head shfl reductions, no LDS.
// Reads S from `out` (d_out) and overwrites the same element per thread.
// ---------------------------------------------------------------------------
__global__ __launch_bounds__(256) void gemm_lang(
    const bf16* __restrict__ A,
    const bf16* __restrict__ Bt,
    const unsigned char* __restrict__ flag,   // [NN*4] validity bytes
    const float* __restrict__ asl_g,          // att_src_lang [128]
    const float* __restrict__ adl_g,          // att_dst_lang [128]
    const float* __restrict__ bias_lang,      // [128]
    float* __restrict__ out)                  // in: S, out: result
{
    __shared__ __align__(16) char smem[20480];
    short (*As)[40] = (short (*)[40])smem;
    short (*Bs)[40] = (short (*)[40])(smem + 10240);

    const int M = NN * NREL;
    const int tid  = threadIdx.x;
    const int wave = tid >> 6, lane = tid & 63;
    const int quad = lane >> 4, l16 = lane & 15;
    const int wq = wave >> 1, wc = wave & 1;
    const int row0 = blockIdx.x * 128;

    floatx4 acc[4][4];
    #pragma unroll
    for (int i = 0; i < 4; ++i)
        #pragma unroll
        for (int j = 0; j < 4; ++j) acc[i][j] = (floatx4){0.f, 0.f, 0.f, 0.f};

    for (int k0 = 0; k0 < 128; k0 += 32) {
        #pragma unroll
        for (int i = 0; i < 2; ++i) {
            int c = tid * 2 + i;
            int r = c >> 2, off = (c & 3) * 8;
            int gr = row0 + r;
            short8 v = {0, 0, 0, 0, 0, 0, 0, 0};
            if (gr < M)
                v = *(const short8*)(A + (((size_t)gr) << 7) + k0 + off);
            *(short8*)&As[r][off] = v;
            short8 w = *(const short8*)(Bt + (((size_t)r) << 7) + k0 + off);
            *(short8*)&Bs[r][off] = w;
        }
        __syncthreads();

        short8 av[4], bv[4];
        #pragma unroll
        for (int mt = 0; mt < 4; ++mt)
            av[mt] = *(const short8*)&As[wq * 64 + mt * 16 + l16][quad * 8];
        #pragma unroll
        for (int nt = 0; nt < 4; ++nt)
            bv[nt] = *(const short8*)&Bs[wc * 64 + nt * 16 + l16][quad * 8];
        #pragma unroll
        for (int mt = 0; mt < 4; ++mt)
            #pragma unroll
            for (int nt = 0; nt < 4; ++nt)
                acc[mt][nt] = __builtin_amdgcn_mfma_f32_16x16x32_bf16(
                    av[mt], bv[nt], acc[mt][nt], 0, 0, 0);
        __syncthreads();
    }

    // ---- fused lang epilogue (no LDS) ----
    const int nb0 = blockIdx.x * 32 + wq * 16;   // this wave's node base
    #pragma unroll
    for (int nt = 0; nt < 4; ++nt) {
        int col = wc * 64 + nt * 16 + l16;
        float asl = asl_g[col];
        float adl = adl_g[col];
        float bl  = bias_lang[col];
        #pragma unroll
        for (int mt = 0; mt < 4; ++mt) {
            int node = nb0 + mt * 4 + quad;
            bool ok = node < NN;
            float Sv = ok ? out[(unsigned)node * 128u + (unsigned)col] : 0.f;
            float h0 = acc[mt][nt][0], h1 = acc[mt][nt][1];
            float h2 = acc[mt][nt][2], h3 = acc[mt][nt][3];
            float t0 = h0 * asl, t1 = h1 * asl, t2 = h2 * asl, t3 = h3 * asl;
            float ts = Sv * asl, td = Sv * adl;
            #pragma unroll
            for (int off = 1; off < 16; off <<= 1) {
                t0 += __shfl_xor(t0, off);
                t1 += __shfl_xor(t1, off);
                t2 += __shfl_xor(t2, off);
                t3 += __shfl_xor(t3, off);
                ts += __shfl_xor(ts, off);
                td += __shfl_xor(td, off);
            }
            unsigned fl = ok ? *(const unsigned*)(flag + (unsigned)node * 4u) : 0u;
            float aS = ts + td, a0 = t0 + td, a1 = t1 + td, a2 = t2 + td, a3 = t3 + td;
            float lS = fmaxf(aS, 0.2f * aS);
            float l0 = fmaxf(a0, 0.2f * a0);
            float l1 = fmaxf(a1, 0.2f * a1);
            float l2 = fmaxf(a2, 0.2f * a2);
            float l3 = fmaxf(a3, 0.2f * a3);
            bool v0 = (fl & 0x000000FFu) != 0, v1 = (fl & 0x0000FF00u) != 0;
            bool v2 = (fl & 0x00FF0000u) != 0, v3 = (fl & 0xFF000000u) != 0;
            float m = lS;
            if (v0) m = fmaxf(m, l0);
            if (v1) m = fmaxf(m, l1);
            if (v2) m = fmaxf(m, l2);
            if (v3) m = fmaxf(m, l3);
            float eS = __expf(lS - m);
            float e0 = v0 ? __expf(l0 - m) : 0.f;
            float e1 = v1 ? __expf(l1 - m) : 0.f;
            float e2 = v2 ? __expf(l2 - m) : 0.f;
            float e3 = v3 ? __expf(l3 - m) : 0.f;
            float sum = eS + e0 + e1 + e2 + e3;
            float o = eS * Sv + e0 * h0 + e1 * h1 + e2 * h2 + e3 * h3;
            o = o / sum + bl;
            if (ok) out[(unsigned)node * 128u + (unsigned)col] = o;
        }
    }
}

// ---------------------------------------------------------------------------
// Counting sort of edges by seg = rel*NN + dst  (histogram / scan / scatter)
// ---------------------------------------------------------------------------
__global__ void hist_kernel(const int* __restrict__ ei, const int* __restrict__ et,
                            int* __restrict__ counts) {
    int e = blockIdx.x * 256 + threadIdx.x;
    if (e >= NE) return;
    int seg = et[e] * NN + ei[NE + e];
    atomicAdd(&counts[seg], 1);
}

__global__ __launch_bounds__(256) void scan1_kernel(const int* __restrict__ counts,
                                                    int* __restrict__ offsets,
                                                    int* __restrict__ partials) {
    __shared__ int sm[256];
    int b = blockIdx.x, t = threadIdx.x, i = b * 256 + t;
    int v = (i < NSEG) ? counts[i] : 0;
    sm[t] = v;
    __syncthreads();
    #pragma unroll
    for (int off = 1; off < 256; off <<= 1) {
        int x = sm[t];
        int y = (t >= off) ? sm[t - off] : 0;
        __syncthreads();
        sm[t] = x + y;
        __syncthreads();
    }
    if (i < NSEG) offsets[i] = sm[t] - v;
    if (t == 255) partials[b] = sm[255];
}

__global__ __launch_bounds__(1024) void scan2_kernel(int* __restrict__ partials,
                                                     int* __restrict__ offsets) {
    __shared__ int sm[1024];
    int t = threadIdx.x;
    int v = (t < NPART) ? partials[t] : 0;
    sm[t] = v;
    __syncthreads();
    #pragma unroll
    for (int off = 1; off < 1024; off <<= 1) {
        int x = sm[t];
        int y = (t >= off) ? sm[t - off] : 0;
        __syncthreads();
        sm[t] = x + y;
        __syncthreads();
    }
    if (t < NPART) partials[t] = sm[t] - v;
    if (t == 0) offsets[NSEG] = NE;
}

__global__ __launch_bounds__(256) void scan3_kernel(int* __restrict__ offsets,
                                                    const int* __restrict__ partials,
                                                    int* __restrict__ cursor) {
    int b = blockIdx.x, i = b * 256 + threadIdx.x;
    if (i >= NSEG) return;
    int v = offsets[i] + partials[b];
    offsets[i] = v;
    cursor[i] = v;
}

__global__ void scatter_kernel(const int* __restrict__ ei, const int* __restrict__ et,
                               int* __restrict__ cursor, int* __restrict__ esrc) {
    int e = blockIdx.x * 256 + threadIdx.x;
    if (e >= NE) return;
    int seg = et[e] * NN + ei[NE + e];
    int pos = atomicAdd(&cursor[seg], 1);
    esrc[pos] = ei[e];
}

// ---------------------------------------------------------------------------
// Batched aggregation: grid.y = rel. 64 lanes per dst node walk its CSR slice.
// Output Gb4 is NODE-MAJOR (row = n*4+rel) for the fused gemm_lang; lane 0
// writes the validity byte flag[n*4+rel].
// ---------------------------------------------------------------------------
__global__ __launch_bounds__(256) void agg_kernel(
    const int* __restrict__ esrc, const int* __restrict__ offsets,
    const bf16* __restrict__ Xb, const float* __restrict__ es,
    const float* __restrict__ ed, const float* __restrict__ bias_rel,
    bf16* __restrict__ Gb4, unsigned char* __restrict__ flag)
{
    const int rel = blockIdx.y;
    const int n = blockIdx.x * 4 + (threadIdx.x >> 6);
    if (n >= NN) return;
    const int l = threadIdx.x & 63;
    const int h = l >> 3;
    const int f = l * 2;
    const unsigned seg = (unsigned)(rel * NN + n);
    int beg = __builtin_amdgcn_readfirstlane(offsets[seg]);
    int end = __builtin_amdgcn_readfirstlane(offsets[seg + 1]);
    const float edv = ed[seg * 8u + (unsigned)h];
    float a0 = 0.f, a1 = 0.f, den = 0.f;
    const unsigned short* Xr = (const unsigned short*)Xb + (unsigned)rel * (unsigned)(NN * 128);
    const float* esr = es + (unsigned)rel * (unsigned)(NN * 8);

    int e = beg;
    for (; e + 3 < end; e += 4) {
        int s0 = __builtin_amdgcn_readfirstlane(esrc[e]);
        int s1 = __builtin_amdgcn_readfirstlane(esrc[e + 1]);
        int s2 = __builtin_amdgcn_readfirstlane(esrc[e + 2]);
        int s3 = __builtin_amdgcn_readfirstlane(esrc[e + 3]);
        float e0 = esr[(unsigned)s0 * 8u + (unsigned)h];
        float e1 = esr[(unsigned)s1 * 8u + (unsigned)h];
        float e2 = esr[(unsigned)s2 * 8u + (unsigned)h];
        float e3 = esr[(unsigned)s3 * 8u + (unsigned)h];
        ushort2 u0 = *(const ushort2*)(Xr + (unsigned)s0 * 128u + (unsigned)f);
        ushort2 u1 = *(const ushort2*)(Xr + (unsigned)s1 * 128u + (unsigned)f);
        ushort2 u2 = *(const ushort2*)(Xr + (unsigned)s2 * 128u + (unsigned)f);
        ushort2 u3 = *(const ushort2*)(Xr + (unsigned)s3 * 128u + (unsigned)f);
        float aa0 = e0 + edv, aa1 = e1 + edv, aa2 = e2 + edv, aa3 = e3 + edv;
        float w0 = __builtin_amdgcn_exp2f(fmaxf(aa0, 0.2f * aa0));
        float w1 = __builtin_amdgcn_exp2f(fmaxf(aa1, 0.2f * aa1));
        float w2 = __builtin_amdgcn_exp2f(fmaxf(aa2, 0.2f * aa2));
        float w3 = __builtin_amdgcn_exp2f(fmaxf(aa3, 0.2f * aa3));
        a0 += w0 * us2f(u0.x) + w1 * us2f(u1.x) + w2 * us2f(u2.x) + w3 * us2f(u3.x);
        a1 += w0 * us2f(u0.y) + w1 * us2f(u1.y) + w2 * us2f(u2.y) + w3 * us2f(u3.y);
        den += (w0 + w1) + (w2 + w3);
    }
    for (; e < end; ++e) {
        int s0 = __builtin_amdgcn_readfirstlane(esrc[e]);
        float e0 = esr[(unsigned)s0 * 8u + (unsigned)h];
        ushort2 u0 = *(const ushort2*)(Xr + (unsigned)s0 * 128u + (unsigned)f);
        float aa0 = e0 + edv;
        float w0 = __builtin_amdgcn_exp2f(fmaxf(aa0, 0.2f * aa0));
        a0 += w0 * us2f(u0.x);
        a1 += w0 * us2f(u0.y);
        den += w0;
    }

    float inv = den > 0.f ? __builtin_amdgcn_rcpf(den) : 0.f;
    float2 bv = *(const float2*)(bias_rel + (unsigned)rel * 128u + (unsigned)f);
    float v0 = __builtin_fmaf(a0, inv, bv.x);
    float v1 = __builtin_fmaf(a1, inv, bv.y);
    v0 = gelu_f(v0);
    v1 = gelu_f(v1);
    bf16 g0 = __float2bfloat16(v0), g1 = __float2bfloat16(v1);
    ushort2 o;
    o.x = *(unsigned short*)&g0;
    o.y = *(unsigned short*)&g1;
    // node-major row for gemm_lang
    *(ushort2*)((unsigned short*)Gb4 + ((unsigned)n * 4u + (unsigned)rel) * 128u + (unsigned)f) = o;
    if (l == 0) flag[(unsigned)n * 4u + (unsigned)rel] = (unsigned char)(end > beg);
}

// ---------------------------------------------------------------------------
extern "C" void kernel_launch(void* const* d_in, const int* in_sizes, int n_in,
                              void* d_out, int out_size, void* d_ws, size_t ws_size,
                              hipStream_t stream) {
    const float* node_inp     = (const float*)d_in[0];
    const int*   edge_index   = (const int*)d_in[1];
    const int*   edge_type    = (const int*)d_in[2];
    const float* W_rel        = (const float*)d_in[3];
    const float* att_src_rel  = (const float*)d_in[4];
    const float* att_dst_rel  = (const float*)d_in[5];
    const float* bias_rel     = (const float*)d_in[6];
    const float* W_self       = (const float*)d_in[7];
    const float* W_cross      = (const float*)d_in[8];
    const float* att_src_lang = (const float*)d_in[9];
    const float* att_dst_lang = (const float*)d_in[10];
    const float* bias_lang    = (const float*)d_in[11];
    (void)in_sizes; (void)n_in;

    // workspace layout (bytes) — total ~120.5 MB (<121.6 MB proven)
    const size_t SZ_XB   = (size_t)NREL * NN * 128 * 2;   // 51,200,000 (bf16)
    const size_t SZ_ES   = (size_t)NREL * NN * 8 * 4;     //  6,400,000
    const size_t SZ_GB4  = (size_t)NREL * NN * 128 * 2;   // 51,200,000 (bf16, node-major)
    const size_t SZ_WT   = 768 * 128 * 2;                 //    196,608
    const size_t SZ_WCT  = 128 * 128 * 2;                 //     32,768
    const size_t SZ_ESRC = (size_t)NE * 4;                //  3,200,000
    const size_t SZ_OFF  = ((size_t)NSEG + 4) * 4;        //    800,016
    const size_t SZ_CNT  = (size_t)NSEG * 4;              //    800,000 (counts/cursor)
    const size_t SZ_PART = 4096;
    const size_t SZ_FLG  = (size_t)NN * 4;                //    200,000
    const size_t TOTAL = SZ_XB + 2 * SZ_ES + SZ_GB4 + SZ_WT + SZ_WCT +
                         SZ_ESRC + SZ_OFF + SZ_CNT + SZ_PART + SZ_FLG;

    if (ws_size < TOTAL) {
        fill_kernel<<<(out_size + 255) / 256, 256, 0, stream>>>((float*)d_out, out_size);
        return;
    }

    char* ws = (char*)d_ws;
    size_t o = 0;
    bf16*  Xb      = (bf16*)(ws + o);  o += SZ_XB;
    float* es      = (float*)(ws + o); o += SZ_ES;
    float* ed      = (float*)(ws + o); o += SZ_ES;
    bf16*  Gb4     = (bf16*)(ws + o);  o += SZ_GB4;
    bf16*  Wt      = (bf16*)(ws + o);  o += SZ_WT;
    bf16*  Wct     = (bf16*)(ws + o);  o += SZ_WCT;
    int*   esrc    = (int*)(ws + o);   o += SZ_ESRC;
    int*   offsets = (int*)(ws + o);   o += SZ_OFF;
    int*   counts  = (int*)(ws + o);   o += SZ_CNT;   // reused as cursor
    int*   partials= (int*)(ws + o);   o += SZ_PART;
    unsigned char* flag = (unsigned char*)(ws + o);
    float* S       = (float*)d_out;  // S scratch in d_out; gemm_lang overwrites

    // pack weights (with log2e-prescaled att columns) + zero counts
    prep_kernel<<<(NSEG + 255) / 256, 256, 0, stream>>>(
        W_rel, W_self, W_cross, att_src_rel, att_dst_rel, Wt, Wct, counts);

    // fused GEMM: Xb (4 relations), S, es, ed in one pass
    dim3 g1((NN + 127) / 128, 6);
    gemm_node<<<g1, 256, 0, stream>>>(node_inp, Wt, Xb, S, es, ed, NN);

    // counting sort by (rel,dst)
    hist_kernel<<<(NE + 255) / 256, 256, 0, stream>>>(edge_index, edge_type, counts);
    scan1_kernel<<<NPART, 256, 0, stream>>>(counts, offsets, partials);
    scan2_kernel<<<1, 1024, 0, stream>>>(partials, offsets);
    scan3_kernel<<<NPART, 256, 0, stream>>>(offsets, partials, counts);
    scatter_kernel<<<(NE + 255) / 256, 256, 0, stream>>>(edge_index, edge_type, counts, esrc);

    // batched aggregation over all relations (node-major output + flags)
    dim3 ga((NN + 3) / 4, NREL);
    agg_kernel<<<ga, 256, 0, stream>>>(esrc, offsets, Xb, es, ed, bias_rel, Gb4, flag);

    // fused cross-GEMM + lang softmax -> d_out
    dim3 g2((NREL * NN + 127) / 128, 1);
    gemm_lang<<<g2, 256, 0, stream>>>(Gb4, Wct, flag, att_src_lang, att_dst_lang,
                                      bias_lang, (float*)d_out);
}